// Round 2
// baseline (743.444 us; speedup 1.0000x reference)
//
#include <hip/hip_runtime.h>

// SimplePoseGNN on MI355X. Inputs/outputs are FP32 (per reference); indices int32.
// Internally: node tensors stored bf16, accumulation fp32, GEMMs via bf16 MFMA.
// Graph conv via CSR-by-dst gather fused into the MFMA kernel (no scatter atomics,
// no fp32 agg buffer). Workspace total ~160.4 MB.

#define NN 139264
#define EE 278528
#define GG 8192
#define NBLK 544    // NN/256
#define EBLK 1088   // EE/256

typedef float f32x4 __attribute__((ext_vector_type(4)));
typedef __bf16 bf16x8 __attribute__((ext_vector_type(8)));
typedef unsigned short u16x8 __attribute__((ext_vector_type(8)));
typedef unsigned short u16x4 __attribute__((ext_vector_type(4)));

__device__ __forceinline__ float bf2f(unsigned short u) {
    unsigned int i = ((unsigned int)u) << 16;
    float f;
    __builtin_memcpy(&f, &i, 4);
    return f;
}
__device__ __forceinline__ unsigned short f2bf(float f) {
    unsigned int i;
    __builtin_memcpy(&i, &f, 4);
    i += 0x7fffu + ((i >> 16) & 1u);   // round-to-nearest-even
    return (unsigned short)(i >> 16);
}

// ---------------- workspace layout (bytes) ----------------
#define OFF_DEG_OUT ((size_t)0)
#define OFF_DEG_IN  ((size_t)557056)
#define OFF_GSUM    ((size_t)1114112)
#define OFF_GCNT    ((size_t)1212416)
#define ZERO_BYTES  ((size_t)1245184)
#define OFF_NOUT    ((size_t)1245184)
#define OFF_NIN     ((size_t)1802240)
#define OFF_ROWPTR  ((size_t)2359296)
#define OFF_CURSOR  ((size_t)2916608)
#define OFF_CSRS    ((size_t)3473664)
#define OFF_BSUM    ((size_t)4587776)
#define OFF_WT1     ((size_t)4591872)
#define OFF_WT2     ((size_t)4722944)
#define OFF_WTA     ((size_t)4854016)
#define OFF_WTB     ((size_t)4985088)
#define OFF_WTCLS   ((size_t)5116160)
#define OFF_BNS     ((size_t)5148928)
#define OFF_BNH     ((size_t)5155072)
#define OFF_Z0      ((size_t)5161216)
#define OFF_Z1      ((size_t)9355520)
#define OFF_Z2      ((size_t)13549824)
#define OFF_X       ((size_t)17744128)
#define OFF_H1      ((size_t)89047296)
// total 160350464 bytes (~160.4 MB)

// ---------------- graph preprocessing ----------------

__global__ void k_deg(const int* __restrict__ src, const int* __restrict__ dst,
                      int* __restrict__ deg_out, int* __restrict__ deg_in) {
    int e = blockIdx.x * 256 + threadIdx.x;
    if (e < EE) {
        atomicAdd(&deg_out[src[e]], 1);
        atomicAdd(&deg_in[dst[e]], 1);
    }
}

// block-level exclusive scan of deg_in -> row_ptr (partial), block totals -> bsum
__global__ void k_scan1(const int* __restrict__ deg, int* __restrict__ part, int* __restrict__ bsum) {
    __shared__ int sh[256];
    int t = threadIdx.x, gid = blockIdx.x * 256 + t;
    int v = deg[gid];
    sh[t] = v;
    __syncthreads();
#pragma unroll
    for (int off = 1; off < 256; off <<= 1) {
        int a = (t >= off) ? sh[t - off] : 0;
        __syncthreads();
        sh[t] += a;
        __syncthreads();
    }
    part[gid] = sh[t] - v;
    if (t == 255) bsum[blockIdx.x] = sh[t];
}

__global__ void k_scan2(int* __restrict__ bsum) {
    __shared__ int sh[1024];
    int t = threadIdx.x;
    int v = (t < NBLK) ? bsum[t] : 0;
    sh[t] = v;
    __syncthreads();
#pragma unroll
    for (int off = 1; off < 1024; off <<= 1) {
        int a = (t >= off) ? sh[t - off] : 0;
        __syncthreads();
        sh[t] += a;
        __syncthreads();
    }
    if (t < NBLK) bsum[t] = sh[t] - v;
}

__global__ void k_scan3(int* __restrict__ rp, const int* __restrict__ bsum, int* __restrict__ cursor) {
    int t = threadIdx.x, gid = blockIdx.x * 256 + t;
    int v = rp[gid] + bsum[blockIdx.x];
    rp[gid] = v;
    cursor[gid] = v;
    if (gid == 0) rp[NN] = EE;
}

__global__ void k_norm(const int* __restrict__ dego, const int* __restrict__ degi,
                       float* __restrict__ n_out, float* __restrict__ n_in) {
    int gid = blockIdx.x * 256 + threadIdx.x;
    n_out[gid] = rsqrtf((float)max(dego[gid], 1));
    n_in[gid]  = rsqrtf((float)max(degi[gid], 1));
}

__global__ void k_fill(const int* __restrict__ src, const int* __restrict__ dst,
                       int* __restrict__ cursor, int* __restrict__ csr) {
    int e = blockIdx.x * 256 + threadIdx.x;
    int d = dst[e];
    int pos = atomicAdd(&cursor[d], 1);
    csr[pos] = src[e];
}

// ---------------- weight prep ----------------

// transpose 4 [256][256] fp32 weights -> bf16 Wt[n][k]
__global__ void k_trans4(const float* __restrict__ w0, const float* __restrict__ w1,
                         const float* __restrict__ w2, const float* __restrict__ w3,
                         unsigned short* __restrict__ t0, unsigned short* __restrict__ t1,
                         unsigned short* __restrict__ t2, unsigned short* __restrict__ t3) {
    int t = blockIdx.x * 256 + threadIdx.x;   // 0..65535
    int k = t >> 8, n = t & 255;
    const float* w = (blockIdx.y == 0) ? w0 : (blockIdx.y == 1) ? w1 : (blockIdx.y == 2) ? w2 : w3;
    unsigned short* o = (blockIdx.y == 0) ? t0 : (blockIdx.y == 1) ? t1 : (blockIdx.y == 2) ? t2 : t3;
    o[n * 256 + k] = f2bf(w[t]);
}

// W_cls fp32 [256][60] -> bf16 Wt [64][256] (zero-padded rows 60..63)
__global__ void k_trans_cls(const float* __restrict__ w, unsigned short* __restrict__ o) {
    int t = blockIdx.x * 256 + threadIdx.x;   // 0..16383
    int n = t >> 8, k = t & 255;
    o[t] = (n < 60) ? f2bf(w[k * 60 + n]) : (unsigned short)0;
}

__global__ void k_bnprep(const float* __restrict__ g, const float* __restrict__ b,
                         const float* __restrict__ m, const float* __restrict__ v,
                         float* __restrict__ bns, float* __restrict__ bnh) {
    int t = blockIdx.x * 256 + threadIdx.x;   // 0..1535
    float inv = rsqrtf(v[t] + 1e-5f);
    float s = g[t] * inv;
    bns[t] = s;
    bnh[t] = b[t] - m[t] * s;
}

// ---------------- embedding ----------------
// x[n][c] = nf[n][0]*Wemb[0][c] + nf[n][1]*Wemb[1][c] + bemb[c]  (fp32 in, bf16 out)
__global__ void k_emb(const float* __restrict__ nf, const float* __restrict__ Wemb,
                      const float* __restrict__ bemb, unsigned short* __restrict__ x) {
    int t = blockIdx.x * 256 + threadIdx.x;   // NN*32 threads
    int n = t >> 5, c = (t & 31) << 3;
    float f0 = nf[2 * n], f1 = nf[2 * n + 1];
    u16x8 o;
#pragma unroll
    for (int j = 0; j < 8; j++)
        o[j] = f2bf(fmaf(f0, Wemb[c + j], fmaf(f1, Wemb[256 + c + j], bemb[c + j])));
    *(u16x8*)(x + (size_t)n * 256 + c) = o;
}

// ---------------- fused gather + GEMM + epilogue ----------------
// Per block: 64 rows, 4 waves; each wave gathers its own 16 rows into a
// XOR-swizzled bf16 LDS tile, then MFMA against Wt[n][k] from global.
// out = resid + relu(bn1(relu(bn0( (gather)*n_in @ W + b ))))
__launch_bounds__(256)
__global__ void k_conv(const unsigned short* __restrict__ xin,
                       const int* __restrict__ csr_src, const int* __restrict__ row_ptr,
                       const float* __restrict__ n_out, const float* __restrict__ n_in,
                       const unsigned short* __restrict__ Wt, const float* __restrict__ bias,
                       const float* __restrict__ bns, const float* __restrict__ bnh, int bnIdx,
                       const unsigned short* __restrict__ resid, unsigned short* __restrict__ out) {
    __shared__ unsigned char smem[4 * 16 * 512];
    int lane = threadIdx.x & 63;
    int wave = threadIdx.x >> 6;
    int wrow = blockIdx.x * 64 + wave * 16;
    unsigned char* wbase = smem + wave * 8192;

    // gather phase (wave-local rows; fp32 accumulate over incident edges)
    for (int rr = 0; rr < 16; rr++) {
        int r = wrow + rr;
        int e0 = row_ptr[r], e1 = row_ptr[r + 1];
        float a0 = 0.f, a1 = 0.f, a2 = 0.f, a3 = 0.f;
        for (int e = e0; e < e1; e++) {
            int s = csr_src[e];
            float sc = n_out[s];
            u16x4 v = *(const u16x4*)(xin + (size_t)s * 256 + lane * 4);
            a0 = fmaf(bf2f(v[0]), sc, a0);
            a1 = fmaf(bf2f(v[1]), sc, a1);
            a2 = fmaf(bf2f(v[2]), sc, a2);
            a3 = fmaf(bf2f(v[3]), sc, a3);
        }
        float sc2 = n_in[r];
        u16x4 o;
        o[0] = f2bf(a0 * sc2); o[1] = f2bf(a1 * sc2);
        o[2] = f2bf(a2 * sc2); o[3] = f2bf(a3 * sc2);
        *(u16x4*)(wbase + rr * 512 + ((lane * 8) ^ ((rr & 7) << 4))) = o;
    }

    // MFMA phase: wave computes 16 rows x 256 cols
    f32x4 acc[16];
    f32x4 zero = {0.f, 0.f, 0.f, 0.f};
#pragma unroll
    for (int i = 0; i < 16; i++) acc[i] = zero;
    int kq = lane >> 4;      // 0..3
    int rsel = lane & 15;
#pragma unroll
    for (int kt = 0; kt < 8; kt++) {
        int cb = kt * 64 + kq * 16;
        u16x8 au = *(const u16x8*)(wbase + rsel * 512 + (cb ^ ((rsel & 7) << 4)));
        bf16x8 af = __builtin_bit_cast(bf16x8, au);
        int k0 = kt * 32 + kq * 8;
#pragma unroll
        for (int nt = 0; nt < 16; nt++) {
            u16x8 bu = *(const u16x8*)(Wt + (size_t)(nt * 16 + rsel) * 256 + k0);
            acc[nt] = __builtin_amdgcn_mfma_f32_16x16x32_bf16(af, __builtin_bit_cast(bf16x8, bu), acc[nt], 0, 0, 0);
        }
    }

    // epilogue
    int colb = lane & 15;
    int rowb = wrow + (kq << 2);
#pragma unroll
    for (int nt = 0; nt < 16; nt++) {
        int col = nt * 16 + colb;
        float bc = bias[col];
        float s0 = bns[bnIdx * 256 + col], h0 = bnh[bnIdx * 256 + col];
        float s1 = bns[(bnIdx + 1) * 256 + col], h1v = bnh[(bnIdx + 1) * 256 + col];
#pragma unroll
        for (int r = 0; r < 4; r++) {
            size_t idx = (size_t)(rowb + r) * 256 + col;
            float y = acc[nt][r] + bc;
            y = fmaxf(fmaf(y, s0, h0), 0.f);
            y = fmaxf(fmaf(y, s1, h1v), 0.f);
            y += bf2f(resid[idx]);
            out[idx] = f2bf(y);
        }
    }
}

// ---------------- pose head + graph pooling ----------------
__global__ void k_out3d(const unsigned short* __restrict__ h2, const float* __restrict__ Wout,
                        const float* __restrict__ bout, const int* __restrict__ n2g,
                        float* __restrict__ h3d, float* __restrict__ gsum, float* __restrict__ gcnt) {
    int lane = threadIdx.x & 63, wave = threadIdx.x >> 6;
    int row = blockIdx.x * 4 + wave;
    int c = lane << 2;
    u16x4 v = *(const u16x4*)(h2 + (size_t)row * 256 + c);
    float p0 = 0.f, p1 = 0.f, p2 = 0.f;
#pragma unroll
    for (int i = 0; i < 4; i++) {
        float hv = bf2f(v[i]);
        const float* wp = Wout + (size_t)(c + i) * 3;
        p0 = fmaf(hv, wp[0], p0);
        p1 = fmaf(hv, wp[1], p1);
        p2 = fmaf(hv, wp[2], p2);
    }
#pragma unroll
    for (int off = 32; off; off >>= 1) {
        p0 += __shfl_down(p0, off);
        p1 += __shfl_down(p1, off);
        p2 += __shfl_down(p2, off);
    }
    if (lane == 0) {
        p0 += bout[0]; p1 += bout[1]; p2 += bout[2];
        size_t o = (size_t)row * 3;
        h3d[o] = p0; h3d[o + 1] = p1; h3d[o + 2] = p2;
        int g = n2g[row];
        unsafeAtomicAdd(&gsum[g * 3 + 0], p0);
        unsafeAtomicAdd(&gsum[g * 3 + 1], p1);
        unsafeAtomicAdd(&gsum[g * 3 + 2], p2);
        unsafeAtomicAdd(&gcnt[g], 1.0f);
    }
}

// z0 = gmean @ W_ci + b_ci  (fp32 in, bf16 out)
__global__ void k_head1(const float* __restrict__ gsum, const float* __restrict__ gcnt,
                        const float* __restrict__ Wci, const float* __restrict__ bci,
                        unsigned short* __restrict__ z0) {
    int t = blockIdx.x * 256 + threadIdx.x;   // GG*32 threads
    int g = t >> 5, c = (t & 31) << 3;
    float cnt = fmaxf(gcnt[g], 1.0f);
    float m0 = gsum[g * 3] / cnt, m1 = gsum[g * 3 + 1] / cnt, m2 = gsum[g * 3 + 2] / cnt;
    u16x8 o;
#pragma unroll
    for (int j = 0; j < 8; j++)
        o[j] = f2bf(fmaf(m0, Wci[c + j], fmaf(m1, Wci[256 + c + j], fmaf(m2, Wci[512 + c + j], bci[c + j]))));
    *(u16x8*)(z0 + (size_t)g * 256 + c) = o;
}

// out = relu(bn(A @ W + b)); A bf16 [rows][256] -> bf16 out
__launch_bounds__(256)
__global__ void k_head_gemm(const unsigned short* __restrict__ A, const unsigned short* __restrict__ Wt,
                            const float* __restrict__ bias, const float* __restrict__ bns,
                            const float* __restrict__ bnh, int bnIdx, unsigned short* __restrict__ out) {
    int lane = threadIdx.x & 63;
    int wave = threadIdx.x >> 6;
    int wrow = blockIdx.x * 64 + wave * 16;
    int arow = wrow + (lane & 15);
    int kb = (lane >> 4) << 3;
    f32x4 zero = {0.f, 0.f, 0.f, 0.f};
    f32x4 acc[16];
#pragma unroll
    for (int i = 0; i < 16; i++) acc[i] = zero;
#pragma unroll
    for (int kt = 0; kt < 8; kt++) {
        int k0 = kt * 32 + kb;
        u16x8 au = *(const u16x8*)(A + (size_t)arow * 256 + k0);
        bf16x8 af = __builtin_bit_cast(bf16x8, au);
#pragma unroll
        for (int nt = 0; nt < 16; nt++) {
            u16x8 bu = *(const u16x8*)(Wt + (size_t)(nt * 16 + (lane & 15)) * 256 + k0);
            acc[nt] = __builtin_amdgcn_mfma_f32_16x16x32_bf16(af, __builtin_bit_cast(bf16x8, bu), acc[nt], 0, 0, 0);
        }
    }
    int colb = lane & 15;
    int rowb = wrow + ((lane >> 4) << 2);
#pragma unroll
    for (int nt = 0; nt < 16; nt++) {
        int col = nt * 16 + colb;
        float bc = bias[col];
        float s0 = bns[bnIdx * 256 + col], h0 = bnh[bnIdx * 256 + col];
#pragma unroll
        for (int r = 0; r < 4; r++) {
            size_t idx = (size_t)(rowb + r) * 256 + col;
            float y = acc[nt][r] + bc;
            y = fmaxf(fmaf(y, s0, h0), 0.f);
            out[idx] = f2bf(y);
        }
    }
}

// label = A @ W_cls + b_cls (fp32 out, 60 cols)
__launch_bounds__(256)
__global__ void k_headcls(const unsigned short* __restrict__ A, const unsigned short* __restrict__ Wt,
                          const float* __restrict__ bias, float* __restrict__ out) {
    int lane = threadIdx.x & 63;
    int wave = threadIdx.x >> 6;
    int wrow = blockIdx.x * 64 + wave * 16;
    int arow = wrow + (lane & 15);
    int kb = (lane >> 4) << 3;
    f32x4 zero = {0.f, 0.f, 0.f, 0.f};
    f32x4 acc[4];
#pragma unroll
    for (int i = 0; i < 4; i++) acc[i] = zero;
#pragma unroll
    for (int kt = 0; kt < 8; kt++) {
        int k0 = kt * 32 + kb;
        u16x8 au = *(const u16x8*)(A + (size_t)arow * 256 + k0);
        bf16x8 af = __builtin_bit_cast(bf16x8, au);
#pragma unroll
        for (int nt = 0; nt < 4; nt++) {
            u16x8 bu = *(const u16x8*)(Wt + (size_t)(nt * 16 + (lane & 15)) * 256 + k0);
            acc[nt] = __builtin_amdgcn_mfma_f32_16x16x32_bf16(af, __builtin_bit_cast(bf16x8, bu), acc[nt], 0, 0, 0);
        }
    }
    int colb = lane & 15;
    int rowb = wrow + ((lane >> 4) << 2);
#pragma unroll
    for (int nt = 0; nt < 4; nt++) {
        int col = nt * 16 + colb;
        if (col < 60) {
            float bc = bias[col];
#pragma unroll
            for (int r = 0; r < 4; r++) {
                out[(size_t)(rowb + r) * 60 + col] = acc[nt][r] + bc;
            }
        }
    }
}

// ---------------- launch ----------------
extern "C" void kernel_launch(void* const* d_in, const int* in_sizes, int n_in,
                              void* d_out, int out_size, void* d_ws, size_t ws_size,
                              hipStream_t stream) {
    const float* nf   = (const float*)d_in[0];
    const int* src    = (const int*)d_in[1];
    const int* dst    = (const int*)d_in[2];
    const int* n2g    = (const int*)d_in[3];
    const float* Wemb = (const float*)d_in[4];
    const float* bemb = (const float*)d_in[5];
    const float* Wc1  = (const float*)d_in[6];
    const float* bc1  = (const float*)d_in[7];
    const float* Wc2  = (const float*)d_in[8];
    const float* bc2  = (const float*)d_in[9];
    const float* bng  = (const float*)d_in[10];
    const float* bnb  = (const float*)d_in[11];
    const float* bnm  = (const float*)d_in[12];
    const float* bnv  = (const float*)d_in[13];
    const float* Wout = (const float*)d_in[14];
    const float* bout = (const float*)d_in[15];
    const float* Wci  = (const float*)d_in[16];
    const float* bci  = (const float*)d_in[17];
    const float* Wb3a = (const float*)d_in[18];
    const float* bb3a = (const float*)d_in[19];
    const float* Wb3b = (const float*)d_in[20];
    const float* bb3b = (const float*)d_in[21];
    const float* Wcls = (const float*)d_in[22];
    const float* bcls = (const float*)d_in[23];

    char* ws = (char*)d_ws;
    int* deg_out = (int*)(ws + OFF_DEG_OUT);
    int* deg_in  = (int*)(ws + OFF_DEG_IN);
    float* gsum  = (float*)(ws + OFF_GSUM);
    float* gcnt  = (float*)(ws + OFF_GCNT);
    float* n_out = (float*)(ws + OFF_NOUT);
    float* n_inp = (float*)(ws + OFF_NIN);
    int* row_ptr = (int*)(ws + OFF_ROWPTR);
    int* cursor  = (int*)(ws + OFF_CURSOR);
    int* csr_src = (int*)(ws + OFF_CSRS);
    int* bsum    = (int*)(ws + OFF_BSUM);
    unsigned short* wt1   = (unsigned short*)(ws + OFF_WT1);
    unsigned short* wt2   = (unsigned short*)(ws + OFF_WT2);
    unsigned short* wta   = (unsigned short*)(ws + OFF_WTA);
    unsigned short* wtb   = (unsigned short*)(ws + OFF_WTB);
    unsigned short* wtcls = (unsigned short*)(ws + OFF_WTCLS);
    float* bns = (float*)(ws + OFF_BNS);
    float* bnh = (float*)(ws + OFF_BNH);
    unsigned short* z0 = (unsigned short*)(ws + OFF_Z0);
    unsigned short* z1 = (unsigned short*)(ws + OFF_Z1);
    unsigned short* z2 = (unsigned short*)(ws + OFF_Z2);
    unsigned short* x  = (unsigned short*)(ws + OFF_X);
    unsigned short* h1 = (unsigned short*)(ws + OFF_H1);

    float* h3d_out   = (float*)d_out;
    float* label_out = (float*)d_out + (size_t)NN * 3;

    hipMemsetAsync(ws, 0, ZERO_BYTES, stream);   // deg_out, deg_in, gsum, gcnt

    // graph structure
    k_deg<<<EBLK, 256, 0, stream>>>(src, dst, deg_out, deg_in);
    k_scan1<<<NBLK, 256, 0, stream>>>(deg_in, row_ptr, bsum);
    k_scan2<<<1, 1024, 0, stream>>>(bsum);
    k_scan3<<<NBLK, 256, 0, stream>>>(row_ptr, bsum, cursor);
    k_norm<<<NBLK, 256, 0, stream>>>(deg_out, deg_in, n_out, n_inp);
    k_fill<<<EBLK, 256, 0, stream>>>(src, dst, cursor, csr_src);

    // weights / bn / embedding
    k_trans4<<<dim3(256, 4), 256, 0, stream>>>(Wc1, Wc2, Wb3a, Wb3b, wt1, wt2, wta, wtb);
    k_trans_cls<<<64, 256, 0, stream>>>(Wcls, wtcls);
    k_bnprep<<<6, 256, 0, stream>>>(bng, bnb, bnm, bnv, bns, bnh);
    k_emb<<<NN / 8, 256, 0, stream>>>(nf, Wemb, bemb, x);

    // conv blocks (fused gather+GEMM+bn+relu+residual)
    k_conv<<<NN / 64, 256, 0, stream>>>(x, csr_src, row_ptr, n_out, n_inp, wt1, bc1, bns, bnh, 0, x, h1);
    k_conv<<<NN / 64, 256, 0, stream>>>(h1, csr_src, row_ptr, n_out, n_inp, wt2, bc2, bns, bnh, 2, h1, x);

    // pose head + graph pooling
    k_out3d<<<NN / 4, 256, 0, stream>>>(x, Wout, bout, n2g, h3d_out, gsum, gcnt);

    // classification head
    k_head1<<<GG / 8, 256, 0, stream>>>(gsum, gcnt, Wci, bci, z0);
    k_head_gemm<<<GG / 64, 256, 0, stream>>>(z0, wta, bb3a, bns, bnh, 4, z1);
    k_head_gemm<<<GG / 64, 256, 0, stream>>>(z1, wtb, bb3b, bns, bnh, 5, z2);
    k_headcls<<<GG / 64, 256, 0, stream>>>(z2, wtcls, bcls, label_out);
}

// Round 3
// 489.361 us; speedup vs baseline: 1.5192x; 1.5192x over previous
//
#include <hip/hip_runtime.h>

// SimplePoseGNN on MI355X — round 3.
// fp32 in/out; internal bf16 tensors + fp32 accumulation; bf16 MFMA GEMMs.
// conv1 input collapsed to 3 scalars/row (DIN=2 trick); conv2 gather split into a
// high-occupancy half-wave-per-row kernel; pose head fused into conv2 epilogue;
// classification head fully fused into one kernel (wave-private LDS tiles).

#define NN 139264
#define EE 278528
#define GG 8192
#define NBLK 544    // NN/256
#define EBLK 1088   // EE/256

typedef float f32x4 __attribute__((ext_vector_type(4)));
typedef __bf16 bf16x8 __attribute__((ext_vector_type(8)));
typedef unsigned short u16x8 __attribute__((ext_vector_type(8)));
typedef unsigned short u16x4 __attribute__((ext_vector_type(4)));

__device__ __forceinline__ float bf2f(unsigned short u) {
    unsigned int i = ((unsigned int)u) << 16;
    float f;
    __builtin_memcpy(&f, &i, 4);
    return f;
}
__device__ __forceinline__ unsigned short f2bf(float f) {
    unsigned int i;
    __builtin_memcpy(&i, &f, 4);
    i += 0x7fffu + ((i >> 16) & 1u);   // round-to-nearest-even
    return (unsigned short)(i >> 16);
}

// ---------------- workspace layout (bytes) ----------------
#define OFF_DEG_OUT ((size_t)0)
#define OFF_DEG_IN  ((size_t)557056)
#define OFF_GSUM    ((size_t)1114112)
#define OFF_GCNT    ((size_t)1212416)
#define ZERO_BYTES  ((size_t)1245184)
#define OFF_NOUT    ((size_t)1245184)
#define OFF_NIN     ((size_t)1802240)
#define OFF_ROWPTR  ((size_t)2359296)
#define OFF_CURSOR  ((size_t)2916608)
#define OFF_CSRS    ((size_t)3473664)
#define OFF_BSUM    ((size_t)4587776)
#define OFF_WT1     ((size_t)4591872)
#define OFF_WT2     ((size_t)4722944)
#define OFF_WTA     ((size_t)4854016)
#define OFF_WTB     ((size_t)4985088)
#define OFF_WTCLS   ((size_t)5116160)
#define OFF_BNS     ((size_t)5148928)
#define OFF_BNH     ((size_t)5155072)
#define OFF_T       ((size_t)5161216)
#define OFF_AGG2    ((size_t)6832384)
#define OFF_H1      ((size_t)78135552)
// total 149438720 (~149.4 MB)

// ---------------- graph preprocessing ----------------

__global__ void k_deg(const int* __restrict__ src, const int* __restrict__ dst,
                      int* __restrict__ deg_out, int* __restrict__ deg_in) {
    int e = blockIdx.x * 256 + threadIdx.x;
    if (e < EE) {
        atomicAdd(&deg_out[src[e]], 1);
        atomicAdd(&deg_in[dst[e]], 1);
    }
}

__global__ void k_scan1(const int* __restrict__ deg, int* __restrict__ part, int* __restrict__ bsum) {
    __shared__ int sh[256];
    int t = threadIdx.x, gid = blockIdx.x * 256 + t;
    int v = deg[gid];
    sh[t] = v;
    __syncthreads();
#pragma unroll
    for (int off = 1; off < 256; off <<= 1) {
        int a = (t >= off) ? sh[t - off] : 0;
        __syncthreads();
        sh[t] += a;
        __syncthreads();
    }
    part[gid] = sh[t] - v;
    if (t == 255) bsum[blockIdx.x] = sh[t];
}

__global__ void k_scan2(int* __restrict__ bsum) {
    __shared__ int sh[1024];
    int t = threadIdx.x;
    int v = (t < NBLK) ? bsum[t] : 0;
    sh[t] = v;
    __syncthreads();
#pragma unroll
    for (int off = 1; off < 1024; off <<= 1) {
        int a = (t >= off) ? sh[t - off] : 0;
        __syncthreads();
        sh[t] += a;
        __syncthreads();
    }
    if (t < NBLK) bsum[t] = sh[t] - v;
}

__global__ void k_scan3(int* __restrict__ rp, const int* __restrict__ bsum, int* __restrict__ cursor) {
    int t = threadIdx.x, gid = blockIdx.x * 256 + t;
    int v = rp[gid] + bsum[blockIdx.x];
    rp[gid] = v;
    cursor[gid] = v;
    if (gid == 0) rp[NN] = EE;
}

__global__ void k_norm(const int* __restrict__ dego, const int* __restrict__ degi,
                       float* __restrict__ n_out, float* __restrict__ n_in) {
    int gid = blockIdx.x * 256 + threadIdx.x;
    n_out[gid] = rsqrtf((float)max(dego[gid], 1));
    n_in[gid]  = rsqrtf((float)max(degi[gid], 1));
}

__global__ void k_fill(const int* __restrict__ src, const int* __restrict__ dst,
                       int* __restrict__ cursor, int* __restrict__ csr) {
    int e = blockIdx.x * 256 + threadIdx.x;
    int d = dst[e];
    int pos = atomicAdd(&cursor[d], 1);
    csr[pos] = src[e];
}

// per-row conv1 stats: T[r] = n_in[r] * { Σ sc*nf0, Σ sc*nf1, Σ sc },  sc = n_out[src]
__global__ void k_rowstats(const int* __restrict__ rp, const int* __restrict__ csr,
                           const float* __restrict__ n_out, const float* __restrict__ n_in,
                           const float* __restrict__ nf, float* __restrict__ T) {
    int r = blockIdx.x * 256 + threadIdx.x;
    int e0 = rp[r], e1 = rp[r + 1];
    float S0 = 0.f, S1 = 0.f, S2 = 0.f;
    for (int e = e0; e < e1; e++) {
        int s = csr[e];
        float sc = n_out[s];
        S0 = fmaf(sc, nf[2 * s], S0);
        S1 = fmaf(sc, nf[2 * s + 1], S1);
        S2 += sc;
    }
    float ni = n_in[r];
    T[3 * r]     = S0 * ni;
    T[3 * r + 1] = S1 * ni;
    T[3 * r + 2] = S2 * ni;
}

// ---------------- weight / bn prep (one kernel) ----------------
__global__ void k_prep(const float* __restrict__ w0, const float* __restrict__ w1,
                       const float* __restrict__ w2, const float* __restrict__ w3,
                       unsigned short* __restrict__ t0, unsigned short* __restrict__ t1,
                       unsigned short* __restrict__ t2, unsigned short* __restrict__ t3,
                       const float* __restrict__ wcls, unsigned short* __restrict__ tcls,
                       const float* __restrict__ g, const float* __restrict__ b,
                       const float* __restrict__ m, const float* __restrict__ v,
                       float* __restrict__ bns, float* __restrict__ bnh) {
    int t = blockIdx.x * 256 + threadIdx.x;
    int y = blockIdx.y;
    if (y < 4) {
        int k = t >> 8, n = t & 255;
        const float* w = (y == 0) ? w0 : (y == 1) ? w1 : (y == 2) ? w2 : w3;
        unsigned short* o = (y == 0) ? t0 : (y == 1) ? t1 : (y == 2) ? t2 : t3;
        o[n * 256 + k] = f2bf(w[t]);
    } else if (y == 4) {
        if (t < 16384) {
            int n = t >> 8, k = t & 255;
            tcls[t] = (n < 60) ? f2bf(wcls[k * 60 + n]) : (unsigned short)0;
        }
    } else {
        if (t < 1536) {
            float inv = rsqrtf(v[t] + 1e-5f);
            float s = g[t] * inv;
            bns[t] = s;
            bnh[t] = b[t] - m[t] * s;
        }
    }
}

// ---------------- conv1: A built on-the-fly from T & Wemb ----------------
// h1 = emb_resid + relu(bn1(relu(bn0( A @ W1 + b1 ))));  A[row][c] = T0*w0[c]+T1*w1[c]+T2*bemb[c]
__launch_bounds__(256)
__global__ void k_conv1(const float* __restrict__ T, const float* __restrict__ nf,
                        const float* __restrict__ Wemb, const float* __restrict__ bemb,
                        const unsigned short* __restrict__ Wt, const float* __restrict__ bias,
                        const float* __restrict__ bns0, const float* __restrict__ bnh0,
                        unsigned short* __restrict__ out) {
    int lane = threadIdx.x & 63, wave = threadIdx.x >> 6;
    int wrow = blockIdx.x * 64 + wave * 16;
    int rsel = lane & 15, kq = lane >> 4;
    int arow = wrow + rsel;
    float t0 = T[3 * arow], t1 = T[3 * arow + 1], t2 = T[3 * arow + 2];
    f32x4 zero = {0.f, 0.f, 0.f, 0.f};
    f32x4 acc[16];
#pragma unroll
    for (int i = 0; i < 16; i++) acc[i] = zero;
#pragma unroll
    for (int kt = 0; kt < 8; kt++) {
        int k0 = kt * 32 + kq * 8;
        u16x8 au;
#pragma unroll
        for (int j = 0; j < 8; j++)
            au[j] = f2bf(fmaf(t0, Wemb[k0 + j], fmaf(t1, Wemb[256 + k0 + j], t2 * bemb[k0 + j])));
        bf16x8 af = __builtin_bit_cast(bf16x8, au);
#pragma unroll
        for (int nt = 0; nt < 16; nt++) {
            u16x8 bu = *(const u16x8*)(Wt + (size_t)(nt * 16 + rsel) * 256 + k0);
            acc[nt] = __builtin_amdgcn_mfma_f32_16x16x32_bf16(af, __builtin_bit_cast(bf16x8, bu), acc[nt], 0, 0, 0);
        }
    }
    int rowb = wrow + kq * 4;
    float f0[4], f1[4];
#pragma unroll
    for (int r = 0; r < 4; r++) {
        float2 p = *(const float2*)(nf + 2 * (size_t)(rowb + r));
        f0[r] = p.x; f1[r] = p.y;
    }
#pragma unroll
    for (int nt = 0; nt < 16; nt++) {
        int col = nt * 16 + rsel;
        float bc = bias[col];
        float s0 = bns0[col], h0 = bnh0[col];
        float s1 = bns0[256 + col], h1v = bnh0[256 + col];
        float we0 = Wemb[col], we1 = Wemb[256 + col], be = bemb[col];
#pragma unroll
        for (int r = 0; r < 4; r++) {
            float y = acc[nt][r] + bc;
            y = fmaxf(fmaf(y, s0, h0), 0.f);
            y = fmaxf(fmaf(y, s1, h1v), 0.f);
            y += fmaf(f0[r], we0, fmaf(f1[r], we1, be));
            out[(size_t)(rowb + r) * 256 + col] = f2bf(y);
        }
    }
}

// ---------------- gather2: one row per half-wave, 16B loads, high occupancy ----------------
__launch_bounds__(256)
__global__ void k_gather2(const int* __restrict__ rp, const int* __restrict__ csr,
                          const float* __restrict__ n_out, const float* __restrict__ n_in,
                          const unsigned short* __restrict__ h1, unsigned short* __restrict__ agg) {
    int hw = threadIdx.x >> 5;           // 0..7 half-waves
    int lane32 = threadIdx.x & 31;
    int row = blockIdx.x * 8 + hw;
    int c = lane32 * 8;
    int e0 = rp[row], e1 = rp[row + 1];
    float a[8] = {0.f, 0.f, 0.f, 0.f, 0.f, 0.f, 0.f, 0.f};
    for (int e = e0; e < e1; e++) {
        int s = csr[e];
        float sc = n_out[s];
        u16x8 v = *(const u16x8*)(h1 + (size_t)s * 256 + c);
#pragma unroll
        for (int j = 0; j < 8; j++) a[j] = fmaf(bf2f(v[j]), sc, a[j]);
    }
    float ni = n_in[row];
    u16x8 o;
#pragma unroll
    for (int j = 0; j < 8; j++) o[j] = f2bf(a[j] * ni);
    *(u16x8*)(agg + (size_t)row * 256 + c) = o;
}

// ---------------- conv2: streaming GEMM + bn/relu/resid + fused pose head ----------------
__launch_bounds__(256)
__global__ void k_conv2(const unsigned short* __restrict__ A, const unsigned short* __restrict__ h1,
                        const unsigned short* __restrict__ Wt, const float* __restrict__ bias,
                        const float* __restrict__ bns0, const float* __restrict__ bnh0,
                        const float* __restrict__ Wout, const float* __restrict__ bout,
                        const int* __restrict__ n2g,
                        float* __restrict__ h3d, float* __restrict__ gsum, float* __restrict__ gcnt) {
    int lane = threadIdx.x & 63, wave = threadIdx.x >> 6;
    int wrow = blockIdx.x * 64 + wave * 16;
    int rsel = lane & 15, kq = lane >> 4;
    int arow = wrow + rsel;
    f32x4 zero = {0.f, 0.f, 0.f, 0.f};
    f32x4 acc[16];
#pragma unroll
    for (int i = 0; i < 16; i++) acc[i] = zero;
#pragma unroll
    for (int kt = 0; kt < 8; kt++) {
        int k0 = kt * 32 + kq * 8;
        u16x8 au = *(const u16x8*)(A + (size_t)arow * 256 + k0);
        bf16x8 af = __builtin_bit_cast(bf16x8, au);
#pragma unroll
        for (int nt = 0; nt < 16; nt++) {
            u16x8 bu = *(const u16x8*)(Wt + (size_t)(nt * 16 + rsel) * 256 + k0);
            acc[nt] = __builtin_amdgcn_mfma_f32_16x16x32_bf16(af, __builtin_bit_cast(bf16x8, bu), acc[nt], 0, 0, 0);
        }
    }
    int rowb = wrow + kq * 4;
    float p0[4] = {0.f, 0.f, 0.f, 0.f};
    float p1[4] = {0.f, 0.f, 0.f, 0.f};
    float p2[4] = {0.f, 0.f, 0.f, 0.f};
#pragma unroll
    for (int nt = 0; nt < 16; nt++) {
        int col = nt * 16 + rsel;
        float bc = bias[col];
        float s0 = bns0[col], h0 = bnh0[col];
        float s1 = bns0[256 + col], h1v = bnh0[256 + col];
        const float* wp = Wout + (size_t)col * 3;
        float w30 = wp[0], w31 = wp[1], w32 = wp[2];
#pragma unroll
        for (int r = 0; r < 4; r++) {
            size_t idx = (size_t)(rowb + r) * 256 + col;
            float y = acc[nt][r] + bc;
            y = fmaxf(fmaf(y, s0, h0), 0.f);
            y = fmaxf(fmaf(y, s1, h1v), 0.f);
            y += bf2f(h1[idx]);                      // residual; h2 never materialized
            p0[r] = fmaf(y, w30, p0[r]);
            p1[r] = fmaf(y, w31, p1[r]);
            p2[r] = fmaf(y, w32, p2[r]);
        }
    }
    // reduce across the 16 lanes of this kq group
#pragma unroll
    for (int m = 1; m < 16; m <<= 1) {
#pragma unroll
        for (int r = 0; r < 4; r++) {
            p0[r] += __shfl_xor(p0[r], m);
            p1[r] += __shfl_xor(p1[r], m);
            p2[r] += __shfl_xor(p2[r], m);
        }
    }
    if (rsel == 0) {
        float b0 = bout[0], b1 = bout[1], b2 = bout[2];
#pragma unroll
        for (int r = 0; r < 4; r++) {
            int row = rowb + r;
            int g = n2g[row];
            float v0 = p0[r] + b0, v1 = p1[r] + b1, v2 = p2[r] + b2;
            h3d[(size_t)row * 3]     = v0;
            h3d[(size_t)row * 3 + 1] = v1;
            h3d[(size_t)row * 3 + 2] = v2;
            unsafeAtomicAdd(&gsum[g * 3], v0);
            unsafeAtomicAdd(&gsum[g * 3 + 1], v1);
            unsafeAtomicAdd(&gsum[g * 3 + 2], v2);
            unsafeAtomicAdd(&gcnt[g], 1.0f);
        }
    }
}

// ---------------- fully fused classification head ----------------
// z0 (on the fly from gmean) -> GEMM wta/bn4/relu -> LDS -> GEMM wtb/bn5/relu -> LDS -> GEMM wtcls -> label
__launch_bounds__(256)
__global__ void k_head(const float* __restrict__ gsum, const float* __restrict__ gcnt,
                       const float* __restrict__ Wci, const float* __restrict__ bci,
                       const unsigned short* __restrict__ wta, const float* __restrict__ ba,
                       const unsigned short* __restrict__ wtb, const float* __restrict__ bb,
                       const unsigned short* __restrict__ wtcls, const float* __restrict__ bcls,
                       const float* __restrict__ bns, const float* __restrict__ bnh,
                       float* __restrict__ label) {
    __shared__ unsigned char smem[65536];     // 2 tiles x 4 waves x 16 rows x 512B
    int lane = threadIdx.x & 63, wave = threadIdx.x >> 6;
    unsigned char* tileA = smem + wave * 8192;
    unsigned char* tileB = smem + 32768 + wave * 8192;
    int wrow = blockIdx.x * 64 + wave * 16;
    int rsel = lane & 15, kq = lane >> 4;
    int arow = wrow + rsel;
    float cnt = fmaxf(gcnt[arow], 1.0f);
    float m0 = gsum[3 * arow] / cnt, m1 = gsum[3 * arow + 1] / cnt, m2 = gsum[3 * arow + 2] / cnt;
    f32x4 zero = {0.f, 0.f, 0.f, 0.f};
    f32x4 acc[16];
#pragma unroll
    for (int i = 0; i < 16; i++) acc[i] = zero;

    // stage 1: z1 = relu(bn4(z0 @ Wa + ba)), z0 built on the fly
#pragma unroll
    for (int kt = 0; kt < 8; kt++) {
        int k0 = kt * 32 + kq * 8;
        u16x8 au;
#pragma unroll
        for (int j = 0; j < 8; j++)
            au[j] = f2bf(fmaf(m0, Wci[k0 + j], fmaf(m1, Wci[256 + k0 + j],
                         fmaf(m2, Wci[512 + k0 + j], bci[k0 + j]))));
        bf16x8 af = __builtin_bit_cast(bf16x8, au);
#pragma unroll
        for (int nt = 0; nt < 16; nt++) {
            u16x8 bu = *(const u16x8*)(wta + (size_t)(nt * 16 + rsel) * 256 + k0);
            acc[nt] = __builtin_amdgcn_mfma_f32_16x16x32_bf16(af, __builtin_bit_cast(bf16x8, bu), acc[nt], 0, 0, 0);
        }
    }
#pragma unroll
    for (int nt = 0; nt < 16; nt++) {
        int col = nt * 16 + rsel;
        float bcv = ba[col];
        float s = bns[4 * 256 + col], h = bnh[4 * 256 + col];
#pragma unroll
        for (int r = 0; r < 4; r++) {
            float y = fmaxf(fmaf(acc[nt][r] + bcv, s, h), 0.f);
            int rr = kq * 4 + r;
            *(unsigned short*)(tileA + rr * 512 + ((col * 2) ^ ((rr & 7) << 4))) = f2bf(y);
        }
    }

    // stage 2: z2 = relu(bn5(z1 @ Wb + bb))
#pragma unroll
    for (int i = 0; i < 16; i++) acc[i] = zero;
#pragma unroll
    for (int kt = 0; kt < 8; kt++) {
        int cb = kt * 64 + kq * 16;
        u16x8 au = *(const u16x8*)(tileA + rsel * 512 + (cb ^ ((rsel & 7) << 4)));
        bf16x8 af = __builtin_bit_cast(bf16x8, au);
        int k0 = kt * 32 + kq * 8;
#pragma unroll
        for (int nt = 0; nt < 16; nt++) {
            u16x8 bu = *(const u16x8*)(wtb + (size_t)(nt * 16 + rsel) * 256 + k0);
            acc[nt] = __builtin_amdgcn_mfma_f32_16x16x32_bf16(af, __builtin_bit_cast(bf16x8, bu), acc[nt], 0, 0, 0);
        }
    }
#pragma unroll
    for (int nt = 0; nt < 16; nt++) {
        int col = nt * 16 + rsel;
        float bcv = bb[col];
        float s = bns[5 * 256 + col], h = bnh[5 * 256 + col];
#pragma unroll
        for (int r = 0; r < 4; r++) {
            float y = fmaxf(fmaf(acc[nt][r] + bcv, s, h), 0.f);
            int rr = kq * 4 + r;
            *(unsigned short*)(tileB + rr * 512 + ((col * 2) ^ ((rr & 7) << 4))) = f2bf(y);
        }
    }

    // stage 3: label = z2 @ Wcls + bcls (60 cols)
    f32x4 acc3[4];
#pragma unroll
    for (int i = 0; i < 4; i++) acc3[i] = zero;
#pragma unroll
    for (int kt = 0; kt < 8; kt++) {
        int cb = kt * 64 + kq * 16;
        u16x8 au = *(const u16x8*)(tileB + rsel * 512 + (cb ^ ((rsel & 7) << 4)));
        bf16x8 af = __builtin_bit_cast(bf16x8, au);
        int k0 = kt * 32 + kq * 8;
#pragma unroll
        for (int nt = 0; nt < 4; nt++) {
            u16x8 bu = *(const u16x8*)(wtcls + (size_t)(nt * 16 + rsel) * 256 + k0);
            acc3[nt] = __builtin_amdgcn_mfma_f32_16x16x32_bf16(af, __builtin_bit_cast(bf16x8, bu), acc3[nt], 0, 0, 0);
        }
    }
    int rowb = wrow + kq * 4;
#pragma unroll
    for (int nt = 0; nt < 4; nt++) {
        int col = nt * 16 + rsel;
        if (col < 60) {
            float bcv = bcls[col];
#pragma unroll
            for (int r = 0; r < 4; r++)
                label[(size_t)(rowb + r) * 60 + col] = acc3[nt][r] + bcv;
        }
    }
}

// ---------------- launch ----------------
extern "C" void kernel_launch(void* const* d_in, const int* in_sizes, int n_in,
                              void* d_out, int out_size, void* d_ws, size_t ws_size,
                              hipStream_t stream) {
    const float* nf   = (const float*)d_in[0];
    const int* src    = (const int*)d_in[1];
    const int* dst    = (const int*)d_in[2];
    const int* n2g    = (const int*)d_in[3];
    const float* Wemb = (const float*)d_in[4];
    const float* bemb = (const float*)d_in[5];
    const float* Wc1  = (const float*)d_in[6];
    const float* bc1  = (const float*)d_in[7];
    const float* Wc2  = (const float*)d_in[8];
    const float* bc2  = (const float*)d_in[9];
    const float* bng  = (const float*)d_in[10];
    const float* bnb  = (const float*)d_in[11];
    const float* bnm  = (const float*)d_in[12];
    const float* bnv  = (const float*)d_in[13];
    const float* Wout = (const float*)d_in[14];
    const float* bout = (const float*)d_in[15];
    const float* Wci  = (const float*)d_in[16];
    const float* bci  = (const float*)d_in[17];
    const float* Wb3a = (const float*)d_in[18];
    const float* bb3a = (const float*)d_in[19];
    const float* Wb3b = (const float*)d_in[20];
    const float* bb3b = (const float*)d_in[21];
    const float* Wcls = (const float*)d_in[22];
    const float* bcls = (const float*)d_in[23];

    char* ws = (char*)d_ws;
    int* deg_out = (int*)(ws + OFF_DEG_OUT);
    int* deg_in  = (int*)(ws + OFF_DEG_IN);
    float* gsum  = (float*)(ws + OFF_GSUM);
    float* gcnt  = (float*)(ws + OFF_GCNT);
    float* n_out = (float*)(ws + OFF_NOUT);
    float* n_inp = (float*)(ws + OFF_NIN);
    int* row_ptr = (int*)(ws + OFF_ROWPTR);
    int* cursor  = (int*)(ws + OFF_CURSOR);
    int* csr_src = (int*)(ws + OFF_CSRS);
    int* bsum    = (int*)(ws + OFF_BSUM);
    unsigned short* wt1   = (unsigned short*)(ws + OFF_WT1);
    unsigned short* wt2   = (unsigned short*)(ws + OFF_WT2);
    unsigned short* wta   = (unsigned short*)(ws + OFF_WTA);
    unsigned short* wtb   = (unsigned short*)(ws + OFF_WTB);
    unsigned short* wtcls = (unsigned short*)(ws + OFF_WTCLS);
    float* bns = (float*)(ws + OFF_BNS);
    float* bnh = (float*)(ws + OFF_BNH);
    float* T   = (float*)(ws + OFF_T);
    unsigned short* agg2 = (unsigned short*)(ws + OFF_AGG2);
    unsigned short* h1   = (unsigned short*)(ws + OFF_H1);

    float* h3d_out   = (float*)d_out;
    float* label_out = (float*)d_out + (size_t)NN * 3;

    hipMemsetAsync(ws, 0, ZERO_BYTES, stream);   // deg_out, deg_in, gsum, gcnt

    k_deg<<<EBLK, 256, 0, stream>>>(src, dst, deg_out, deg_in);
    k_scan1<<<NBLK, 256, 0, stream>>>(deg_in, row_ptr, bsum);
    k_scan2<<<1, 1024, 0, stream>>>(bsum);
    k_scan3<<<NBLK, 256, 0, stream>>>(row_ptr, bsum, cursor);
    k_norm<<<NBLK, 256, 0, stream>>>(deg_out, deg_in, n_out, n_inp);
    k_fill<<<EBLK, 256, 0, stream>>>(src, dst, cursor, csr_src);
    k_prep<<<dim3(256, 6), 256, 0, stream>>>(Wc1, Wc2, Wb3a, Wb3b, wt1, wt2, wta, wtb,
                                             Wcls, wtcls, bng, bnb, bnm, bnv, bns, bnh);
    k_rowstats<<<NBLK, 256, 0, stream>>>(row_ptr, csr_src, n_out, n_inp, nf, T);

    k_conv1<<<NN / 64, 256, 0, stream>>>(T, nf, Wemb, bemb, wt1, bc1, bns, bnh, h1);
    k_gather2<<<NN / 8, 256, 0, stream>>>(row_ptr, csr_src, n_out, n_inp, h1, agg2);
    k_conv2<<<NN / 64, 256, 0, stream>>>(agg2, h1, wt2, bc2, bns + 512, bnh + 512,
                                         Wout, bout, n2g, h3d_out, gsum, gcnt);
    k_head<<<GG / 64, 256, 0, stream>>>(gsum, gcnt, Wci, bci, wta, bb3a, wtb, bb3b,
                                        wtcls, bcls, bns, bnh, label_out);
}

// Round 4
// 338.343 us; speedup vs baseline: 2.1973x; 1.4463x over previous
//
#include <hip/hip_runtime.h>

// SimplePoseGNN on MI355X — round 4.
// fp32 in/out; internal bf16 tensors + fp32 accumulation; bf16 MFMA GEMMs.
// Conv GEMMs restructured: 64 rows x 256 cols per block, 4 waves col-partitioned,
// 64x64 register tile per wave (acc[4][4]) -> 4x less L2 B-traffic, 8 independent
// loads per K-step. Pose head fused into conv2 with LDS cross-wave reduce.

#define NN 139264
#define EE 278528
#define GG 8192
#define NBLK 544    // NN/256
#define EBLK 1088   // EE/256

typedef float f32x4 __attribute__((ext_vector_type(4)));
typedef __bf16 bf16x8 __attribute__((ext_vector_type(8)));
typedef unsigned short u16x8 __attribute__((ext_vector_type(8)));
typedef unsigned short u16x4 __attribute__((ext_vector_type(4)));

__device__ __forceinline__ float bf2f(unsigned short u) {
    unsigned int i = ((unsigned int)u) << 16;
    float f;
    __builtin_memcpy(&f, &i, 4);
    return f;
}
__device__ __forceinline__ unsigned short f2bf(float f) {
    unsigned int i;
    __builtin_memcpy(&i, &f, 4);
    i += 0x7fffu + ((i >> 16) & 1u);   // round-to-nearest-even
    return (unsigned short)(i >> 16);
}

// ---------------- workspace layout (bytes) ----------------
#define OFF_DEG_OUT ((size_t)0)
#define OFF_DEG_IN  ((size_t)557056)
#define OFF_GSUM    ((size_t)1114112)
#define OFF_GCNT    ((size_t)1212416)
#define ZERO_BYTES  ((size_t)1245184)
#define OFF_NOUT    ((size_t)1245184)
#define OFF_NIN     ((size_t)1802240)
#define OFF_ROWPTR  ((size_t)2359296)
#define OFF_CURSOR  ((size_t)2916608)
#define OFF_CSRS    ((size_t)3473664)
#define OFF_BSUM    ((size_t)4587776)
#define OFF_WT1     ((size_t)4591872)
#define OFF_WT2     ((size_t)4722944)
#define OFF_WTA     ((size_t)4854016)
#define OFF_WTB     ((size_t)4985088)
#define OFF_WTCLS   ((size_t)5116160)
#define OFF_BNS     ((size_t)5148928)
#define OFF_BNH     ((size_t)5155072)
#define OFF_T       ((size_t)5161216)
#define OFF_AGG2    ((size_t)6832384)
#define OFF_H1      ((size_t)78135552)
// total 149438720 (~149.4 MB)

// ---------------- graph preprocessing ----------------

__global__ void k_deg(const int* __restrict__ src, const int* __restrict__ dst,
                      int* __restrict__ deg_out, int* __restrict__ deg_in) {
    int e = blockIdx.x * 256 + threadIdx.x;
    if (e < EE) {
        atomicAdd(&deg_out[src[e]], 1);
        atomicAdd(&deg_in[dst[e]], 1);
    }
}

__global__ void k_scan1(const int* __restrict__ deg, int* __restrict__ part, int* __restrict__ bsum) {
    __shared__ int sh[256];
    int t = threadIdx.x, gid = blockIdx.x * 256 + t;
    int v = deg[gid];
    sh[t] = v;
    __syncthreads();
#pragma unroll
    for (int off = 1; off < 256; off <<= 1) {
        int a = (t >= off) ? sh[t - off] : 0;
        __syncthreads();
        sh[t] += a;
        __syncthreads();
    }
    part[gid] = sh[t] - v;
    if (t == 255) bsum[blockIdx.x] = sh[t];
}

__global__ void k_scan2(int* __restrict__ bsum) {
    __shared__ int sh[1024];
    int t = threadIdx.x;
    int v = (t < NBLK) ? bsum[t] : 0;
    sh[t] = v;
    __syncthreads();
#pragma unroll
    for (int off = 1; off < 1024; off <<= 1) {
        int a = (t >= off) ? sh[t - off] : 0;
        __syncthreads();
        sh[t] += a;
        __syncthreads();
    }
    if (t < NBLK) bsum[t] = sh[t] - v;
}

__global__ void k_scan3(int* __restrict__ rp, const int* __restrict__ bsum, int* __restrict__ cursor) {
    int t = threadIdx.x, gid = blockIdx.x * 256 + t;
    int v = rp[gid] + bsum[blockIdx.x];
    rp[gid] = v;
    cursor[gid] = v;
    if (gid == 0) rp[NN] = EE;
}

__global__ void k_norm(const int* __restrict__ dego, const int* __restrict__ degi,
                       float* __restrict__ n_out, float* __restrict__ n_in) {
    int gid = blockIdx.x * 256 + threadIdx.x;
    n_out[gid] = rsqrtf((float)max(dego[gid], 1));
    n_in[gid]  = rsqrtf((float)max(degi[gid], 1));
}

__global__ void k_fill(const int* __restrict__ src, const int* __restrict__ dst,
                       int* __restrict__ cursor, int* __restrict__ csr) {
    int e = blockIdx.x * 256 + threadIdx.x;
    int d = dst[e];
    int pos = atomicAdd(&cursor[d], 1);
    csr[pos] = src[e];
}

// per-row conv1 stats: T[r] = n_in[r] * { Σ sc*nf0, Σ sc*nf1, Σ sc },  sc = n_out[src]
__global__ void k_rowstats(const int* __restrict__ rp, const int* __restrict__ csr,
                           const float* __restrict__ n_out, const float* __restrict__ n_in,
                           const float* __restrict__ nf, float* __restrict__ T) {
    int r = blockIdx.x * 256 + threadIdx.x;
    int e0 = rp[r], e1 = rp[r + 1];
    float S0 = 0.f, S1 = 0.f, S2 = 0.f;
    for (int e = e0; e < e1; e++) {
        int s = csr[e];
        float sc = n_out[s];
        S0 = fmaf(sc, nf[2 * s], S0);
        S1 = fmaf(sc, nf[2 * s + 1], S1);
        S2 += sc;
    }
    float ni = n_in[r];
    T[3 * r]     = S0 * ni;
    T[3 * r + 1] = S1 * ni;
    T[3 * r + 2] = S2 * ni;
}

// ---------------- weight / bn prep ----------------
__global__ void k_prep(const float* __restrict__ w0, const float* __restrict__ w1,
                       const float* __restrict__ w2, const float* __restrict__ w3,
                       unsigned short* __restrict__ t0, unsigned short* __restrict__ t1,
                       unsigned short* __restrict__ t2, unsigned short* __restrict__ t3,
                       const float* __restrict__ wcls, unsigned short* __restrict__ tcls,
                       const float* __restrict__ g, const float* __restrict__ b,
                       const float* __restrict__ m, const float* __restrict__ v,
                       float* __restrict__ bns, float* __restrict__ bnh) {
    int t = blockIdx.x * 256 + threadIdx.x;
    int y = blockIdx.y;
    if (y < 4) {
        int k = t >> 8, n = t & 255;
        const float* w = (y == 0) ? w0 : (y == 1) ? w1 : (y == 2) ? w2 : w3;
        unsigned short* o = (y == 0) ? t0 : (y == 1) ? t1 : (y == 2) ? t2 : t3;
        o[n * 256 + k] = f2bf(w[t]);
    } else if (y == 4) {
        if (t < 16384) {
            int n = t >> 8, k = t & 255;
            tcls[t] = (n < 60) ? f2bf(wcls[k * 60 + n]) : (unsigned short)0;
        }
    } else {
        if (t < 1536) {
            float inv = rsqrtf(v[t] + 1e-5f);
            float s = g[t] * inv;
            bns[t] = s;
            bnh[t] = b[t] - m[t] * s;
        }
    }
}

// ---------------- conv1: 64x64 wave tiles, A on-the-fly from T & Wemb ----------------
// h1 = emb_resid + relu(bn1(relu(bn0( A @ W1 + b1 ))))
__launch_bounds__(256)
__global__ void k_conv1(const float* __restrict__ T, const float* __restrict__ nf,
                        const float* __restrict__ Wemb, const float* __restrict__ bemb,
                        const unsigned short* __restrict__ Wt, const float* __restrict__ bias,
                        const float* __restrict__ bns0, const float* __restrict__ bnh0,
                        unsigned short* __restrict__ out) {
    int lane = threadIdx.x & 63, wave = threadIdx.x >> 6;
    int wrow = blockIdx.x * 64;
    int rsel = lane & 15, kq = lane >> 4;
    float t0[4], t1[4], t2[4];
#pragma unroll
    for (int mt = 0; mt < 4; mt++) {
        int r = wrow + mt * 16 + rsel;
        t0[mt] = T[3 * r]; t1[mt] = T[3 * r + 1]; t2[mt] = T[3 * r + 2];
    }
    f32x4 acc[4][4];
    f32x4 zero = {0.f, 0.f, 0.f, 0.f};
#pragma unroll
    for (int i = 0; i < 4; i++)
#pragma unroll
        for (int j = 0; j < 4; j++) acc[i][j] = zero;

#pragma unroll
    for (int kt = 0; kt < 8; kt++) {
        int k0 = kt * 32 + kq * 8;
        float w0s[8], w1s[8], bes[8];
        *(float4*)w0s = *(const float4*)(Wemb + k0);       *(float4*)(w0s + 4) = *(const float4*)(Wemb + k0 + 4);
        *(float4*)w1s = *(const float4*)(Wemb + 256 + k0); *(float4*)(w1s + 4) = *(const float4*)(Wemb + 256 + k0 + 4);
        *(float4*)bes = *(const float4*)(bemb + k0);       *(float4*)(bes + 4) = *(const float4*)(bemb + k0 + 4);
        bf16x8 afr[4];
#pragma unroll
        for (int mt = 0; mt < 4; mt++) {
            u16x8 au;
#pragma unroll
            for (int j = 0; j < 8; j++)
                au[j] = f2bf(fmaf(t0[mt], w0s[j], fmaf(t1[mt], w1s[j], t2[mt] * bes[j])));
            afr[mt] = __builtin_bit_cast(bf16x8, au);
        }
        bf16x8 bfr[4];
#pragma unroll
        for (int nt = 0; nt < 4; nt++) {
            u16x8 bu = *(const u16x8*)(Wt + (size_t)(wave * 64 + nt * 16 + rsel) * 256 + k0);
            bfr[nt] = __builtin_bit_cast(bf16x8, bu);
        }
#pragma unroll
        for (int mt = 0; mt < 4; mt++)
#pragma unroll
            for (int nt = 0; nt < 4; nt++)
                acc[mt][nt] = __builtin_amdgcn_mfma_f32_16x16x32_bf16(afr[mt], bfr[nt], acc[mt][nt], 0, 0, 0);
    }

    // epilogue
#pragma unroll
    for (int mt = 0; mt < 4; mt++) {
        float f0[4], f1[4];
#pragma unroll
        for (int r = 0; r < 4; r++) {
            int row = wrow + mt * 16 + kq * 4 + r;
            float2 p = *(const float2*)(nf + 2 * (size_t)row);
            f0[r] = p.x; f1[r] = p.y;
        }
#pragma unroll
        for (int nt = 0; nt < 4; nt++) {
            int col = wave * 64 + nt * 16 + rsel;
            float bc = bias[col];
            float s0 = bns0[col], h0 = bnh0[col];
            float s1 = bns0[256 + col], h1v = bnh0[256 + col];
            float we0 = Wemb[col], we1 = Wemb[256 + col], be = bemb[col];
#pragma unroll
            for (int r = 0; r < 4; r++) {
                int row = wrow + mt * 16 + kq * 4 + r;
                float y = acc[mt][nt][r] + bc;
                y = fmaxf(fmaf(y, s0, h0), 0.f);
                y = fmaxf(fmaf(y, s1, h1v), 0.f);
                y += fmaf(f0[r], we0, fmaf(f1[r], we1, be));
                out[(size_t)row * 256 + col] = f2bf(y);
            }
        }
    }
}

// ---------------- gather2: one row per half-wave ----------------
__launch_bounds__(256)
__global__ void k_gather2(const int* __restrict__ rp, const int* __restrict__ csr,
                          const float* __restrict__ n_out, const float* __restrict__ n_in,
                          const unsigned short* __restrict__ h1, unsigned short* __restrict__ agg) {
    int hw = threadIdx.x >> 5;
    int lane32 = threadIdx.x & 31;
    int row = blockIdx.x * 8 + hw;
    int c = lane32 * 8;
    int e0 = rp[row], e1 = rp[row + 1];
    float a[8] = {0.f, 0.f, 0.f, 0.f, 0.f, 0.f, 0.f, 0.f};
    for (int e = e0; e < e1; e++) {
        int s = csr[e];
        float sc = n_out[s];
        u16x8 v = *(const u16x8*)(h1 + (size_t)s * 256 + c);
#pragma unroll
        for (int j = 0; j < 8; j++) a[j] = fmaf(bf2f(v[j]), sc, a[j]);
    }
    float ni = n_in[row];
    u16x8 o;
#pragma unroll
    for (int j = 0; j < 8; j++) o[j] = f2bf(a[j] * ni);
    *(u16x8*)(agg + (size_t)row * 256 + c) = o;
}

// ---------------- conv2: 64x64 wave tiles + bn/relu/resid + fused pose head ----------------
__launch_bounds__(256)
__global__ void k_conv2(const unsigned short* __restrict__ A, const unsigned short* __restrict__ h1,
                        const unsigned short* __restrict__ Wt, const float* __restrict__ bias,
                        const float* __restrict__ bns0, const float* __restrict__ bnh0,
                        const float* __restrict__ Wout, const float* __restrict__ bout,
                        const int* __restrict__ n2g,
                        float* __restrict__ h3d, float* __restrict__ gsum, float* __restrict__ gcnt) {
    __shared__ float pl[4][64][3];
    int lane = threadIdx.x & 63, wave = threadIdx.x >> 6;
    int wrow = blockIdx.x * 64;
    int rsel = lane & 15, kq = lane >> 4;
    f32x4 acc[4][4];
    f32x4 zero = {0.f, 0.f, 0.f, 0.f};
#pragma unroll
    for (int i = 0; i < 4; i++)
#pragma unroll
        for (int j = 0; j < 4; j++) acc[i][j] = zero;

#pragma unroll
    for (int kt = 0; kt < 8; kt++) {
        int k0 = kt * 32 + kq * 8;
        bf16x8 afr[4];
#pragma unroll
        for (int mt = 0; mt < 4; mt++) {
            u16x8 au = *(const u16x8*)(A + (size_t)(wrow + mt * 16 + rsel) * 256 + k0);
            afr[mt] = __builtin_bit_cast(bf16x8, au);
        }
        bf16x8 bfr[4];
#pragma unroll
        for (int nt = 0; nt < 4; nt++) {
            u16x8 bu = *(const u16x8*)(Wt + (size_t)(wave * 64 + nt * 16 + rsel) * 256 + k0);
            bfr[nt] = __builtin_bit_cast(bf16x8, bu);
        }
#pragma unroll
        for (int mt = 0; mt < 4; mt++)
#pragma unroll
            for (int nt = 0; nt < 4; nt++)
                acc[mt][nt] = __builtin_amdgcn_mfma_f32_16x16x32_bf16(afr[mt], bfr[nt], acc[mt][nt], 0, 0, 0);
    }

    // epilogue: bn/relu/resid, pose partials over this wave's 64 cols
#pragma unroll
    for (int mt = 0; mt < 4; mt++) {
        float p0[4] = {0.f, 0.f, 0.f, 0.f};
        float p1[4] = {0.f, 0.f, 0.f, 0.f};
        float p2[4] = {0.f, 0.f, 0.f, 0.f};
#pragma unroll
        for (int nt = 0; nt < 4; nt++) {
            int col = wave * 64 + nt * 16 + rsel;
            float bc = bias[col];
            float s0 = bns0[col], h0 = bnh0[col];
            float s1 = bns0[256 + col], h1v = bnh0[256 + col];
            const float* wp = Wout + (size_t)col * 3;
            float w30 = wp[0], w31 = wp[1], w32 = wp[2];
#pragma unroll
            for (int r = 0; r < 4; r++) {
                int row = wrow + mt * 16 + kq * 4 + r;
                float y = acc[mt][nt][r] + bc;
                y = fmaxf(fmaf(y, s0, h0), 0.f);
                y = fmaxf(fmaf(y, s1, h1v), 0.f);
                y += bf2f(h1[(size_t)row * 256 + col]);
                p0[r] = fmaf(y, w30, p0[r]);
                p1[r] = fmaf(y, w31, p1[r]);
                p2[r] = fmaf(y, w32, p2[r]);
            }
        }
#pragma unroll
        for (int m = 1; m < 16; m <<= 1) {
#pragma unroll
            for (int r = 0; r < 4; r++) {
                p0[r] += __shfl_xor(p0[r], m);
                p1[r] += __shfl_xor(p1[r], m);
                p2[r] += __shfl_xor(p2[r], m);
            }
        }
        if (rsel == 0) {
#pragma unroll
            for (int r = 0; r < 4; r++) {
                int lrow = mt * 16 + kq * 4 + r;
                pl[wave][lrow][0] = p0[r];
                pl[wave][lrow][1] = p1[r];
                pl[wave][lrow][2] = p2[r];
            }
        }
    }
    __syncthreads();
    int tid = threadIdx.x;
    if (tid < 192) {
        int lrow = tid / 3, c = tid % 3;
        int row = wrow + lrow;
        float v = pl[0][lrow][c] + pl[1][lrow][c] + pl[2][lrow][c] + pl[3][lrow][c] + bout[c];
        h3d[(size_t)row * 3 + c] = v;
        int g = n2g[row];
        unsafeAtomicAdd(&gsum[g * 3 + c], v);
        if (c == 0) unsafeAtomicAdd(&gcnt[g], 1.0f);
    }
}

// ---------------- fully fused classification head ----------------
__launch_bounds__(256)
__global__ void k_head(const float* __restrict__ gsum, const float* __restrict__ gcnt,
                       const float* __restrict__ Wci, const float* __restrict__ bci,
                       const unsigned short* __restrict__ wta, const float* __restrict__ ba,
                       const unsigned short* __restrict__ wtb, const float* __restrict__ bb,
                       const unsigned short* __restrict__ wtcls, const float* __restrict__ bcls,
                       const float* __restrict__ bns, const float* __restrict__ bnh,
                       float* __restrict__ label) {
    __shared__ unsigned char smem[65536];
    int lane = threadIdx.x & 63, wave = threadIdx.x >> 6;
    unsigned char* tileA = smem + wave * 8192;
    unsigned char* tileB = smem + 32768 + wave * 8192;
    int wrow = blockIdx.x * 64 + wave * 16;
    int rsel = lane & 15, kq = lane >> 4;
    int arow = wrow + rsel;
    float cnt = fmaxf(gcnt[arow], 1.0f);
    float m0 = gsum[3 * arow] / cnt, m1 = gsum[3 * arow + 1] / cnt, m2 = gsum[3 * arow + 2] / cnt;
    f32x4 zero = {0.f, 0.f, 0.f, 0.f};
    f32x4 acc[16];
#pragma unroll
    for (int i = 0; i < 16; i++) acc[i] = zero;

    // stage 1: z1 = relu(bn4(z0 @ Wa + ba)), z0 built on the fly
#pragma unroll
    for (int kt = 0; kt < 8; kt++) {
        int k0 = kt * 32 + kq * 8;
        u16x8 au;
#pragma unroll
        for (int j = 0; j < 8; j++)
            au[j] = f2bf(fmaf(m0, Wci[k0 + j], fmaf(m1, Wci[256 + k0 + j],
                         fmaf(m2, Wci[512 + k0 + j], bci[k0 + j]))));
        bf16x8 af = __builtin_bit_cast(bf16x8, au);
#pragma unroll
        for (int nt = 0; nt < 16; nt++) {
            u16x8 bu = *(const u16x8*)(wta + (size_t)(nt * 16 + rsel) * 256 + k0);
            acc[nt] = __builtin_amdgcn_mfma_f32_16x16x32_bf16(af, __builtin_bit_cast(bf16x8, bu), acc[nt], 0, 0, 0);
        }
    }
#pragma unroll
    for (int nt = 0; nt < 16; nt++) {
        int col = nt * 16 + rsel;
        float bcv = ba[col];
        float s = bns[4 * 256 + col], h = bnh[4 * 256 + col];
#pragma unroll
        for (int r = 0; r < 4; r++) {
            float y = fmaxf(fmaf(acc[nt][r] + bcv, s, h), 0.f);
            int rr = kq * 4 + r;
            *(unsigned short*)(tileA + rr * 512 + ((col * 2) ^ ((rr & 7) << 4))) = f2bf(y);
        }
    }

    // stage 2: z2 = relu(bn5(z1 @ Wb + bb))
#pragma unroll
    for (int i = 0; i < 16; i++) acc[i] = zero;
#pragma unroll
    for (int kt = 0; kt < 8; kt++) {
        int cb = kt * 64 + kq * 16;
        u16x8 au = *(const u16x8*)(tileA + rsel * 512 + (cb ^ ((rsel & 7) << 4)));
        bf16x8 af = __builtin_bit_cast(bf16x8, au);
        int k0 = kt * 32 + kq * 8;
#pragma unroll
        for (int nt = 0; nt < 16; nt++) {
            u16x8 bu = *(const u16x8*)(wtb + (size_t)(nt * 16 + rsel) * 256 + k0);
            acc[nt] = __builtin_amdgcn_mfma_f32_16x16x32_bf16(af, __builtin_bit_cast(bf16x8, bu), acc[nt], 0, 0, 0);
        }
    }
#pragma unroll
    for (int nt = 0; nt < 16; nt++) {
        int col = nt * 16 + rsel;
        float bcv = bb[col];
        float s = bns[5 * 256 + col], h = bnh[5 * 256 + col];
#pragma unroll
        for (int r = 0; r < 4; r++) {
            float y = fmaxf(fmaf(acc[nt][r] + bcv, s, h), 0.f);
            int rr = kq * 4 + r;
            *(unsigned short*)(tileB + rr * 512 + ((col * 2) ^ ((rr & 7) << 4))) = f2bf(y);
        }
    }

    // stage 3: label = z2 @ Wcls + bcls (60 cols)
    f32x4 acc3[4];
#pragma unroll
    for (int i = 0; i < 4; i++) acc3[i] = zero;
#pragma unroll
    for (int kt = 0; kt < 8; kt++) {
        int cb = kt * 64 + kq * 16;
        u16x8 au = *(const u16x8*)(tileB + rsel * 512 + (cb ^ ((rsel & 7) << 4)));
        bf16x8 af = __builtin_bit_cast(bf16x8, au);
        int k0 = kt * 32 + kq * 8;
#pragma unroll
        for (int nt = 0; nt < 4; nt++) {
            u16x8 bu = *(const u16x8*)(wtcls + (size_t)(nt * 16 + rsel) * 256 + k0);
            acc3[nt] = __builtin_amdgcn_mfma_f32_16x16x32_bf16(af, __builtin_bit_cast(bf16x8, bu), acc3[nt], 0, 0, 0);
        }
    }
    int rowb = wrow + kq * 4;
#pragma unroll
    for (int nt = 0; nt < 4; nt++) {
        int col = nt * 16 + rsel;
        if (col < 60) {
            float bcv = bcls[col];
#pragma unroll
            for (int r = 0; r < 4; r++)
                label[(size_t)(rowb + r) * 60 + col] = acc3[nt][r] + bcv;
        }
    }
}

// ---------------- launch ----------------
extern "C" void kernel_launch(void* const* d_in, const int* in_sizes, int n_in,
                              void* d_out, int out_size, void* d_ws, size_t ws_size,
                              hipStream_t stream) {
    const float* nf   = (const float*)d_in[0];
    const int* src    = (const int*)d_in[1];
    const int* dst    = (const int*)d_in[2];
    const int* n2g    = (const int*)d_in[3];
    const float* Wemb = (const float*)d_in[4];
    const float* bemb = (const float*)d_in[5];
    const float* Wc1  = (const float*)d_in[6];
    const float* bc1  = (const float*)d_in[7];
    const float* Wc2  = (const float*)d_in[8];
    const float* bc2  = (const float*)d_in[9];
    const float* bng  = (const float*)d_in[10];
    const float* bnb  = (const float*)d_in[11];
    const float* bnm  = (const float*)d_in[12];
    const float* bnv  = (const float*)d_in[13];
    const float* Wout = (const float*)d_in[14];
    const float* bout = (const float*)d_in[15];
    const float* Wci  = (const float*)d_in[16];
    const float* bci  = (const float*)d_in[17];
    const float* Wb3a = (const float*)d_in[18];
    const float* bb3a = (const float*)d_in[19];
    const float* Wb3b = (const float*)d_in[20];
    const float* bb3b = (const float*)d_in[21];
    const float* Wcls = (const float*)d_in[22];
    const float* bcls = (const float*)d_in[23];

    char* ws = (char*)d_ws;
    int* deg_out = (int*)(ws + OFF_DEG_OUT);
    int* deg_in  = (int*)(ws + OFF_DEG_IN);
    float* gsum  = (float*)(ws + OFF_GSUM);
    float* gcnt  = (float*)(ws + OFF_GCNT);
    float* n_out = (float*)(ws + OFF_NOUT);
    float* n_inp = (float*)(ws + OFF_NIN);
    int* row_ptr = (int*)(ws + OFF_ROWPTR);
    int* cursor  = (int*)(ws + OFF_CURSOR);
    int* csr_src = (int*)(ws + OFF_CSRS);
    int* bsum    = (int*)(ws + OFF_BSUM);
    unsigned short* wt1   = (unsigned short*)(ws + OFF_WT1);
    unsigned short* wt2   = (unsigned short*)(ws + OFF_WT2);
    unsigned short* wta   = (unsigned short*)(ws + OFF_WTA);
    unsigned short* wtb   = (unsigned short*)(ws + OFF_WTB);
    unsigned short* wtcls = (unsigned short*)(ws + OFF_WTCLS);
    float* bns = (float*)(ws + OFF_BNS);
    float* bnh = (float*)(ws + OFF_BNH);
    float* T   = (float*)(ws + OFF_T);
    unsigned short* agg2 = (unsigned short*)(ws + OFF_AGG2);
    unsigned short* h1   = (unsigned short*)(ws + OFF_H1);

    float* h3d_out   = (float*)d_out;
    float* label_out = (float*)d_out + (size_t)NN * 3;

    hipMemsetAsync(ws, 0, ZERO_BYTES, stream);   // deg_out, deg_in, gsum, gcnt

    k_deg<<<EBLK, 256, 0, stream>>>(src, dst, deg_out, deg_in);
    k_scan1<<<NBLK, 256, 0, stream>>>(deg_in, row_ptr, bsum);
    k_scan2<<<1, 1024, 0, stream>>>(bsum);
    k_scan3<<<NBLK, 256, 0, stream>>>(row_ptr, bsum, cursor);
    k_norm<<<NBLK, 256, 0, stream>>>(deg_out, deg_in, n_out, n_inp);
    k_fill<<<EBLK, 256, 0, stream>>>(src, dst, cursor, csr_src);
    k_prep<<<dim3(256, 6), 256, 0, stream>>>(Wc1, Wc2, Wb3a, Wb3b, wt1, wt2, wta, wtb,
                                             Wcls, wtcls, bng, bnb, bnm, bnv, bns, bnh);
    k_rowstats<<<NBLK, 256, 0, stream>>>(row_ptr, csr_src, n_out, n_inp, nf, T);

    k_conv1<<<NN / 64, 256, 0, stream>>>(T, nf, Wemb, bemb, wt1, bc1, bns, bnh, h1);
    k_gather2<<<NN / 8, 256, 0, stream>>>(row_ptr, csr_src, n_out, n_inp, h1, agg2);
    k_conv2<<<NN / 64, 256, 0, stream>>>(agg2, h1, wt2, bc2, bns + 512, bnh + 512,
                                         Wout, bout, n2g, h3d_out, gsum, gcnt);
    k_head<<<GG / 64, 256, 0, stream>>>(gsum, gcnt, Wci, bci, wta, bb3a, wtb, bb3b,
                                        wtcls, bcls, bns, bnh, label_out);
}

// Round 5
// 310.902 us; speedup vs baseline: 2.3913x; 1.0883x over previous
//
#include <hip/hip_runtime.h>

// SimplePoseGNN on MI355X — round 5.
// fp32 in/out; internal bf16 + fp32 accumulation; bf16 MFMA GEMMs.
// Key structure: h2 never exists (residual folded into R3 = h1@Wout computed in
// conv1); conv1 stores h1 pre-scaled by n_out; conv2 fuses CSR gather (LDS tile)
// + GEMM + pose head; graph mean via binary search on sorted node2graph (no atomics).

#define NN 139264
#define EE 278528
#define GG 8192
#define NBLK 544    // NN/256
#define EBLK 1088   // EE/256

typedef float f32x4 __attribute__((ext_vector_type(4)));
typedef __bf16 bf16x8 __attribute__((ext_vector_type(8)));
typedef unsigned short u16x8 __attribute__((ext_vector_type(8)));

__device__ __forceinline__ float bf2f(unsigned short u) {
    unsigned int i = ((unsigned int)u) << 16;
    float f;
    __builtin_memcpy(&f, &i, 4);
    return f;
}
__device__ __forceinline__ unsigned short f2bf(float f) {
    unsigned int i;
    __builtin_memcpy(&i, &f, 4);
    i += 0x7fffu + ((i >> 16) & 1u);   // round-to-nearest-even
    return (unsigned short)(i >> 16);
}

// ---------------- workspace layout (bytes) ----------------
#define OFF_DEG_OUT ((size_t)0)
#define OFF_DEG_IN  ((size_t)557056)
#define ZERO_BYTES  ((size_t)1114112)
#define OFF_NOUT    ((size_t)1114112)
#define OFF_NIN     ((size_t)1671168)
#define OFF_ROWPTR  ((size_t)2228224)
#define OFF_CURSOR  ((size_t)2788352)
#define OFF_CSRS    ((size_t)3345408)
#define OFF_BSUM    ((size_t)4459520)
#define OFF_WT1     ((size_t)4463616)
#define OFF_WT2     ((size_t)4594688)
#define OFF_WTA     ((size_t)4725760)
#define OFF_WTB     ((size_t)4856832)
#define OFF_WTCLS   ((size_t)4987904)
#define OFF_BNS     ((size_t)5020672)
#define OFF_BNH     ((size_t)5026816)
#define OFF_T       ((size_t)5032960)
#define OFF_R3      ((size_t)6704128)
#define OFF_H1S     ((size_t)8375296)
// total ~79.7 MB

// ---------------- graph preprocessing ----------------

__global__ void k_deg(const int* __restrict__ src, const int* __restrict__ dst,
                      int* __restrict__ deg_out, int* __restrict__ deg_in) {
    int e = blockIdx.x * 256 + threadIdx.x;
    if (e < EE) {
        atomicAdd(&deg_out[src[e]], 1);
        atomicAdd(&deg_in[dst[e]], 1);
    }
}

__global__ void k_scan1(const int* __restrict__ deg, int* __restrict__ part, int* __restrict__ bsum) {
    __shared__ int sh[256];
    int t = threadIdx.x, gid = blockIdx.x * 256 + t;
    int v = deg[gid];
    sh[t] = v;
    __syncthreads();
#pragma unroll
    for (int off = 1; off < 256; off <<= 1) {
        int a = (t >= off) ? sh[t - off] : 0;
        __syncthreads();
        sh[t] += a;
        __syncthreads();
    }
    part[gid] = sh[t] - v;
    if (t == 255) bsum[blockIdx.x] = sh[t];
}

__global__ void k_scan2(int* __restrict__ bsum) {
    __shared__ int sh[1024];
    int t = threadIdx.x;
    int v = (t < NBLK) ? bsum[t] : 0;
    sh[t] = v;
    __syncthreads();
#pragma unroll
    for (int off = 1; off < 1024; off <<= 1) {
        int a = (t >= off) ? sh[t - off] : 0;
        __syncthreads();
        sh[t] += a;
        __syncthreads();
    }
    if (t < NBLK) bsum[t] = sh[t] - v;
}

// scan finalize + cursor copy + norm factors
__global__ void k_scan3(int* __restrict__ rp, const int* __restrict__ bsum, int* __restrict__ cursor,
                        const int* __restrict__ dego, const int* __restrict__ degi,
                        float* __restrict__ n_out, float* __restrict__ n_in) {
    int t = threadIdx.x, gid = blockIdx.x * 256 + t;
    int v = rp[gid] + bsum[blockIdx.x];
    rp[gid] = v;
    cursor[gid] = v;
    if (gid == 0) rp[NN] = EE;
    n_out[gid] = rsqrtf((float)max(dego[gid], 1));
    n_in[gid]  = rsqrtf((float)max(degi[gid], 1));
}

__global__ void k_fill(const int* __restrict__ src, const int* __restrict__ dst,
                       int* __restrict__ cursor, int* __restrict__ csr) {
    int e = blockIdx.x * 256 + threadIdx.x;
    int d = dst[e];
    int pos = atomicAdd(&cursor[d], 1);
    csr[pos] = src[e];
}

// per-row conv1 stats: T[r] = n_in[r] * { Σ sc*nf0, Σ sc*nf1, Σ sc },  sc = n_out[src]
__global__ void k_rowstats(const int* __restrict__ rp, const int* __restrict__ csr,
                           const float* __restrict__ n_out, const float* __restrict__ n_in,
                           const float* __restrict__ nf, float* __restrict__ T) {
    int r = blockIdx.x * 256 + threadIdx.x;
    int e0 = rp[r], e1 = rp[r + 1];
    float S0 = 0.f, S1 = 0.f, S2 = 0.f;
    for (int e = e0; e < e1; e++) {
        int s = csr[e];
        float sc = n_out[s];
        S0 = fmaf(sc, nf[2 * s], S0);
        S1 = fmaf(sc, nf[2 * s + 1], S1);
        S2 += sc;
    }
    float ni = n_in[r];
    T[3 * r]     = S0 * ni;
    T[3 * r + 1] = S1 * ni;
    T[3 * r + 2] = S2 * ni;
}

// ---------------- weight / bn prep ----------------
__global__ void k_prep(const float* __restrict__ w0, const float* __restrict__ w1,
                       const float* __restrict__ w2, const float* __restrict__ w3,
                       unsigned short* __restrict__ t0, unsigned short* __restrict__ t1,
                       unsigned short* __restrict__ t2, unsigned short* __restrict__ t3,
                       const float* __restrict__ wcls, unsigned short* __restrict__ tcls,
                       const float* __restrict__ g, const float* __restrict__ b,
                       const float* __restrict__ m, const float* __restrict__ v,
                       float* __restrict__ bns, float* __restrict__ bnh) {
    int t = blockIdx.x * 256 + threadIdx.x;
    int y = blockIdx.y;
    if (y < 4) {
        int k = t >> 8, n = t & 255;
        const float* w = (y == 0) ? w0 : (y == 1) ? w1 : (y == 2) ? w2 : w3;
        unsigned short* o = (y == 0) ? t0 : (y == 1) ? t1 : (y == 2) ? t2 : t3;
        o[n * 256 + k] = f2bf(w[t]);
    } else if (y == 4) {
        if (t < 16384) {
            int n = t >> 8, k = t & 255;
            tcls[t] = (n < 60) ? f2bf(wcls[k * 60 + n]) : (unsigned short)0;
        }
    } else {
        if (t < 1536) {
            float inv = rsqrtf(v[t] + 1e-5f);
            float s = g[t] * inv;
            bns[t] = s;
            bnh[t] = b[t] - m[t] * s;
        }
    }
}

// ---------------- conv1: 64x64 wave tiles; writes h1s (pre-scaled) + R3 ----------------
// y = emb_resid + relu(bn1(relu(bn0( A @ W1 + b1 ))));  h1s = y * n_out[row]; R3 = y @ Wout
__launch_bounds__(256)
__global__ void k_conv1(const float* __restrict__ T, const float* __restrict__ nf,
                        const float* __restrict__ Wemb, const float* __restrict__ bemb,
                        const unsigned short* __restrict__ Wt, const float* __restrict__ bias,
                        const float* __restrict__ bns0, const float* __restrict__ bnh0,
                        const float* __restrict__ Wout, const float* __restrict__ n_out,
                        unsigned short* __restrict__ h1s, float* __restrict__ R3) {
    __shared__ float pl[4][64][3];
    int lane = threadIdx.x & 63, wave = threadIdx.x >> 6;
    int wrow = blockIdx.x * 64;
    int rsel = lane & 15, kq = lane >> 4;
    float t0[4], t1[4], t2[4];
#pragma unroll
    for (int mt = 0; mt < 4; mt++) {
        int r = wrow + mt * 16 + rsel;
        t0[mt] = T[3 * r]; t1[mt] = T[3 * r + 1]; t2[mt] = T[3 * r + 2];
    }
    f32x4 acc[4][4];
    f32x4 zero = {0.f, 0.f, 0.f, 0.f};
#pragma unroll
    for (int i = 0; i < 4; i++)
#pragma unroll
        for (int j = 0; j < 4; j++) acc[i][j] = zero;

#pragma unroll
    for (int kt = 0; kt < 8; kt++) {
        int k0 = kt * 32 + kq * 8;
        float w0s[8], w1s[8], bes[8];
        *(float4*)w0s = *(const float4*)(Wemb + k0);       *(float4*)(w0s + 4) = *(const float4*)(Wemb + k0 + 4);
        *(float4*)w1s = *(const float4*)(Wemb + 256 + k0); *(float4*)(w1s + 4) = *(const float4*)(Wemb + 256 + k0 + 4);
        *(float4*)bes = *(const float4*)(bemb + k0);       *(float4*)(bes + 4) = *(const float4*)(bemb + k0 + 4);
        bf16x8 afr[4];
#pragma unroll
        for (int mt = 0; mt < 4; mt++) {
            u16x8 au;
#pragma unroll
            for (int j = 0; j < 8; j++)
                au[j] = f2bf(fmaf(t0[mt], w0s[j], fmaf(t1[mt], w1s[j], t2[mt] * bes[j])));
            afr[mt] = __builtin_bit_cast(bf16x8, au);
        }
        bf16x8 bfr[4];
#pragma unroll
        for (int nt = 0; nt < 4; nt++) {
            u16x8 bu = *(const u16x8*)(Wt + (size_t)(wave * 64 + nt * 16 + rsel) * 256 + k0);
            bfr[nt] = __builtin_bit_cast(bf16x8, bu);
        }
#pragma unroll
        for (int mt = 0; mt < 4; mt++)
#pragma unroll
            for (int nt = 0; nt < 4; nt++)
                acc[mt][nt] = __builtin_amdgcn_mfma_f32_16x16x32_bf16(afr[mt], bfr[nt], acc[mt][nt], 0, 0, 0);
    }

    // epilogue: bn chain + emb residual; store h1s (scaled); pose partials -> R3
#pragma unroll
    for (int mt = 0; mt < 4; mt++) {
        float f0[4], f1[4], no[4];
        float p0[4] = {0.f, 0.f, 0.f, 0.f};
        float p1[4] = {0.f, 0.f, 0.f, 0.f};
        float p2[4] = {0.f, 0.f, 0.f, 0.f};
#pragma unroll
        for (int r = 0; r < 4; r++) {
            int row = wrow + mt * 16 + kq * 4 + r;
            float2 p = *(const float2*)(nf + 2 * (size_t)row);
            f0[r] = p.x; f1[r] = p.y;
            no[r] = n_out[row];
        }
#pragma unroll
        for (int nt = 0; nt < 4; nt++) {
            int col = wave * 64 + nt * 16 + rsel;
            float bc = bias[col];
            float s0 = bns0[col], h0 = bnh0[col];
            float s1 = bns0[256 + col], h1v = bnh0[256 + col];
            float we0 = Wemb[col], we1 = Wemb[256 + col], be = bemb[col];
            const float* wp = Wout + (size_t)col * 3;
            float w30 = wp[0], w31 = wp[1], w32 = wp[2];
#pragma unroll
            for (int r = 0; r < 4; r++) {
                int row = wrow + mt * 16 + kq * 4 + r;
                float y = acc[mt][nt][r] + bc;
                y = fmaxf(fmaf(y, s0, h0), 0.f);
                y = fmaxf(fmaf(y, s1, h1v), 0.f);
                y += fmaf(f0[r], we0, fmaf(f1[r], we1, be));
                h1s[(size_t)row * 256 + col] = f2bf(y * no[r]);
                p0[r] = fmaf(y, w30, p0[r]);
                p1[r] = fmaf(y, w31, p1[r]);
                p2[r] = fmaf(y, w32, p2[r]);
            }
        }
#pragma unroll
        for (int m = 1; m < 16; m <<= 1) {
#pragma unroll
            for (int r = 0; r < 4; r++) {
                p0[r] += __shfl_xor(p0[r], m);
                p1[r] += __shfl_xor(p1[r], m);
                p2[r] += __shfl_xor(p2[r], m);
            }
        }
        if (rsel == 0) {
#pragma unroll
            for (int r = 0; r < 4; r++) {
                int lrow = mt * 16 + kq * 4 + r;
                pl[wave][lrow][0] = p0[r];
                pl[wave][lrow][1] = p1[r];
                pl[wave][lrow][2] = p2[r];
            }
        }
    }
    __syncthreads();
    int tid = threadIdx.x;
    if (tid < 192) {
        int lrow = tid / 3, c = tid % 3;
        R3[(size_t)(wrow + lrow) * 3 + c] =
            pl[0][lrow][c] + pl[1][lrow][c] + pl[2][lrow][c] + pl[3][lrow][c];
    }
}

// ---------------- conv2: fused CSR gather (LDS) + GEMM + pose head ----------------
// agg = (Σ_src h1s[src]) * n_in[row];  y = relu(bn3(relu(bn2(agg@W2 + b2))));
// h3d[row] = y@Wout + R3[row] + bout.  No atomics, no h2, no resid read.
__launch_bounds__(256)
__global__ void k_conv2(const int* __restrict__ rp, const int* __restrict__ csr,
                        const float* __restrict__ n_in, const unsigned short* __restrict__ h1s,
                        const unsigned short* __restrict__ Wt, const float* __restrict__ bias,
                        const float* __restrict__ bns0, const float* __restrict__ bnh0,
                        const float* __restrict__ Wout, const float* __restrict__ bout,
                        const float* __restrict__ R3, float* __restrict__ h3d) {
    __shared__ unsigned char tileA[64 * 512];   // swizzled bf16 A-tile
    __shared__ float pl[4][64][3];
    int lane = threadIdx.x & 63, wave = threadIdx.x >> 6;
    int wrow = blockIdx.x * 64;
    int rsel = lane & 15, kq = lane >> 4;

    // gather phase: one row per quarter-wave (16 rows in flight), 4 iterations
    int qw = threadIdx.x >> 4;        // 0..15
    int l16 = threadIdx.x & 15;
    int c0 = l16 * 16;                // 16 channels per lane
#pragma unroll
    for (int it = 0; it < 4; it++) {
        int rr = it * 16 + qw;
        int r = wrow + rr;
        int e0 = rp[r], e1 = rp[r + 1];
        float a[16];
#pragma unroll
        for (int j = 0; j < 16; j++) a[j] = 0.f;
        for (int e = e0; e < e1; e++) {
            int s = csr[e];
            const unsigned short* hp = h1s + (size_t)s * 256 + c0;
            u16x8 v0 = *(const u16x8*)hp;
            u16x8 v1 = *(const u16x8*)(hp + 8);
#pragma unroll
            for (int j = 0; j < 8; j++) {
                a[j]     = fmaf(bf2f(v0[j]), 1.f, a[j]);
                a[8 + j] = fmaf(bf2f(v1[j]), 1.f, a[8 + j]);
            }
        }
        float ni = n_in[r];
        u16x8 o0, o1;
#pragma unroll
        for (int j = 0; j < 8; j++) {
            o0[j] = f2bf(a[j] * ni);
            o1[j] = f2bf(a[8 + j] * ni);
        }
        int sw = (rr & 7) << 4;
        *(u16x8*)(tileA + rr * 512 + ((c0 * 2) ^ sw)) = o0;
        *(u16x8*)(tileA + rr * 512 + (((c0 * 2) + 16) ^ sw)) = o1;
    }
    __syncthreads();

    // GEMM: 64x64 per wave, A from LDS, B from global (L2-resident)
    f32x4 acc[4][4];
    f32x4 zero = {0.f, 0.f, 0.f, 0.f};
#pragma unroll
    for (int i = 0; i < 4; i++)
#pragma unroll
        for (int j = 0; j < 4; j++) acc[i][j] = zero;
#pragma unroll
    for (int kt = 0; kt < 8; kt++) {
        int cb = kt * 64 + kq * 16;
        int k0 = kt * 32 + kq * 8;
        bf16x8 afr[4];
#pragma unroll
        for (int mt = 0; mt < 4; mt++) {
            int ar = mt * 16 + rsel;
            u16x8 au = *(const u16x8*)(tileA + ar * 512 + (cb ^ ((ar & 7) << 4)));
            afr[mt] = __builtin_bit_cast(bf16x8, au);
        }
        bf16x8 bfr[4];
#pragma unroll
        for (int nt = 0; nt < 4; nt++) {
            u16x8 bu = *(const u16x8*)(Wt + (size_t)(wave * 64 + nt * 16 + rsel) * 256 + k0);
            bfr[nt] = __builtin_bit_cast(bf16x8, bu);
        }
#pragma unroll
        for (int mt = 0; mt < 4; mt++)
#pragma unroll
            for (int nt = 0; nt < 4; nt++)
                acc[mt][nt] = __builtin_amdgcn_mfma_f32_16x16x32_bf16(afr[mt], bfr[nt], acc[mt][nt], 0, 0, 0);
    }

    // epilogue: bn/relu, pose partials over this wave's 64 cols
#pragma unroll
    for (int mt = 0; mt < 4; mt++) {
        float p0[4] = {0.f, 0.f, 0.f, 0.f};
        float p1[4] = {0.f, 0.f, 0.f, 0.f};
        float p2[4] = {0.f, 0.f, 0.f, 0.f};
#pragma unroll
        for (int nt = 0; nt < 4; nt++) {
            int col = wave * 64 + nt * 16 + rsel;
            float bc = bias[col];
            float s0 = bns0[col], h0 = bnh0[col];
            float s1 = bns0[256 + col], h1v = bnh0[256 + col];
            const float* wp = Wout + (size_t)col * 3;
            float w30 = wp[0], w31 = wp[1], w32 = wp[2];
#pragma unroll
            for (int r = 0; r < 4; r++) {
                float y = acc[mt][nt][r] + bc;
                y = fmaxf(fmaf(y, s0, h0), 0.f);
                y = fmaxf(fmaf(y, s1, h1v), 0.f);
                p0[r] = fmaf(y, w30, p0[r]);
                p1[r] = fmaf(y, w31, p1[r]);
                p2[r] = fmaf(y, w32, p2[r]);
            }
        }
#pragma unroll
        for (int m = 1; m < 16; m <<= 1) {
#pragma unroll
            for (int r = 0; r < 4; r++) {
                p0[r] += __shfl_xor(p0[r], m);
                p1[r] += __shfl_xor(p1[r], m);
                p2[r] += __shfl_xor(p2[r], m);
            }
        }
        if (rsel == 0) {
#pragma unroll
            for (int r = 0; r < 4; r++) {
                int lrow = mt * 16 + kq * 4 + r;
                pl[wave][lrow][0] = p0[r];
                pl[wave][lrow][1] = p1[r];
                pl[wave][lrow][2] = p2[r];
            }
        }
    }
    __syncthreads();
    int tid = threadIdx.x;
    if (tid < 192) {
        int lrow = tid / 3, c = tid % 3;
        int row = wrow + lrow;
        h3d[(size_t)row * 3 + c] =
            pl[0][lrow][c] + pl[1][lrow][c] + pl[2][lrow][c] + pl[3][lrow][c]
            + R3[(size_t)row * 3 + c] + bout[c];
    }
}

// ---------------- fused classification head (gmean via binary search) ----------------
__launch_bounds__(256)
__global__ void k_head(const int* __restrict__ n2g, const float* __restrict__ h3d,
                       const float* __restrict__ Wci, const float* __restrict__ bci,
                       const unsigned short* __restrict__ wta, const float* __restrict__ ba,
                       const unsigned short* __restrict__ wtb, const float* __restrict__ bb,
                       const unsigned short* __restrict__ wtcls, const float* __restrict__ bcls,
                       const float* __restrict__ bns, const float* __restrict__ bnh,
                       float* __restrict__ label) {
    __shared__ unsigned char smem[65536];
    int lane = threadIdx.x & 63, wave = threadIdx.x >> 6;
    unsigned char* tileA = smem + wave * 8192;
    unsigned char* tileB = smem + 32768 + wave * 8192;
    int wrow = blockIdx.x * 64 + wave * 16;
    int rsel = lane & 15, kq = lane >> 4;
    int g = wrow + rsel;              // graph id for this lane

    // graph node range via binary search on sorted n2g
    int lo = 0, hi = NN;
    while (lo < hi) { int mid = (lo + hi) >> 1; if (n2g[mid] < g) lo = mid + 1; else hi = mid; }
    int s = lo;
    hi = NN;
    while (lo < hi) { int mid = (lo + hi) >> 1; if (n2g[mid] < g + 1) lo = mid + 1; else hi = mid; }
    int e = lo;
    float m0 = 0.f, m1 = 0.f, m2 = 0.f;
    for (int j = s; j < e; j++) {
        m0 += h3d[(size_t)j * 3];
        m1 += h3d[(size_t)j * 3 + 1];
        m2 += h3d[(size_t)j * 3 + 2];
    }
    float inv = 1.f / fmaxf((float)(e - s), 1.f);
    m0 *= inv; m1 *= inv; m2 *= inv;

    f32x4 zero = {0.f, 0.f, 0.f, 0.f};
    f32x4 acc[16];
#pragma unroll
    for (int i = 0; i < 16; i++) acc[i] = zero;

    // stage 1: z1 = relu(bn4(z0 @ Wa + ba)), z0 built on the fly
#pragma unroll
    for (int kt = 0; kt < 8; kt++) {
        int k0 = kt * 32 + kq * 8;
        u16x8 au;
#pragma unroll
        for (int j = 0; j < 8; j++)
            au[j] = f2bf(fmaf(m0, Wci[k0 + j], fmaf(m1, Wci[256 + k0 + j],
                         fmaf(m2, Wci[512 + k0 + j], bci[k0 + j]))));
        bf16x8 af = __builtin_bit_cast(bf16x8, au);
#pragma unroll
        for (int nt = 0; nt < 16; nt++) {
            u16x8 bu = *(const u16x8*)(wta + (size_t)(nt * 16 + rsel) * 256 + k0);
            acc[nt] = __builtin_amdgcn_mfma_f32_16x16x32_bf16(af, __builtin_bit_cast(bf16x8, bu), acc[nt], 0, 0, 0);
        }
    }
#pragma unroll
    for (int nt = 0; nt < 16; nt++) {
        int col = nt * 16 + rsel;
        float bcv = ba[col];
        float sc = bns[4 * 256 + col], h = bnh[4 * 256 + col];
#pragma unroll
        for (int r = 0; r < 4; r++) {
            float y = fmaxf(fmaf(acc[nt][r] + bcv, sc, h), 0.f);
            int rr = kq * 4 + r;
            *(unsigned short*)(tileA + rr * 512 + ((col * 2) ^ ((rr & 7) << 4))) = f2bf(y);
        }
    }

    // stage 2: z2 = relu(bn5(z1 @ Wb + bb))
#pragma unroll
    for (int i = 0; i < 16; i++) acc[i] = zero;
#pragma unroll
    for (int kt = 0; kt < 8; kt++) {
        int cb = kt * 64 + kq * 16;
        u16x8 au = *(const u16x8*)(tileA + rsel * 512 + (cb ^ ((rsel & 7) << 4)));
        bf16x8 af = __builtin_bit_cast(bf16x8, au);
        int k0 = kt * 32 + kq * 8;
#pragma unroll
        for (int nt = 0; nt < 16; nt++) {
            u16x8 bu = *(const u16x8*)(wtb + (size_t)(nt * 16 + rsel) * 256 + k0);
            acc[nt] = __builtin_amdgcn_mfma_f32_16x16x32_bf16(af, __builtin_bit_cast(bf16x8, bu), acc[nt], 0, 0, 0);
        }
    }
#pragma unroll
    for (int nt = 0; nt < 16; nt++) {
        int col = nt * 16 + rsel;
        float bcv = bb[col];
        float sc = bns[5 * 256 + col], h = bnh[5 * 256 + col];
#pragma unroll
        for (int r = 0; r < 4; r++) {
            float y = fmaxf(fmaf(acc[nt][r] + bcv, sc, h), 0.f);
            int rr = kq * 4 + r;
            *(unsigned short*)(tileB + rr * 512 + ((col * 2) ^ ((rr & 7) << 4))) = f2bf(y);
        }
    }

    // stage 3: label = z2 @ Wcls + bcls (60 cols)
    f32x4 acc3[4];
#pragma unroll
    for (int i = 0; i < 4; i++) acc3[i] = zero;
#pragma unroll
    for (int kt = 0; kt < 8; kt++) {
        int cb = kt * 64 + kq * 16;
        u16x8 au = *(const u16x8*)(tileB + rsel * 512 + (cb ^ ((rsel & 7) << 4)));
        bf16x8 af = __builtin_bit_cast(bf16x8, au);
        int k0 = kt * 32 + kq * 8;
#pragma unroll
        for (int nt = 0; nt < 4; nt++) {
            u16x8 bu = *(const u16x8*)(wtcls + (size_t)(nt * 16 + rsel) * 256 + k0);
            acc3[nt] = __builtin_amdgcn_mfma_f32_16x16x32_bf16(af, __builtin_bit_cast(bf16x8, bu), acc3[nt], 0, 0, 0);
        }
    }
    int rowb = wrow + kq * 4;
#pragma unroll
    for (int nt = 0; nt < 4; nt++) {
        int col = nt * 16 + rsel;
        if (col < 60) {
            float bcv = bcls[col];
#pragma unroll
            for (int r = 0; r < 4; r++)
                label[(size_t)(rowb + r) * 60 + col] = acc3[nt][r] + bcv;
        }
    }
}

// ---------------- launch ----------------
extern "C" void kernel_launch(void* const* d_in, const int* in_sizes, int n_in,
                              void* d_out, int out_size, void* d_ws, size_t ws_size,
                              hipStream_t stream) {
    const float* nf   = (const float*)d_in[0];
    const int* src    = (const int*)d_in[1];
    const int* dst    = (const int*)d_in[2];
    const int* n2g    = (const int*)d_in[3];
    const float* Wemb = (const float*)d_in[4];
    const float* bemb = (const float*)d_in[5];
    const float* Wc1  = (const float*)d_in[6];
    const float* bc1  = (const float*)d_in[7];
    const float* Wc2  = (const float*)d_in[8];
    const float* bc2  = (const float*)d_in[9];
    const float* bng  = (const float*)d_in[10];
    const float* bnb  = (const float*)d_in[11];
    const float* bnm  = (const float*)d_in[12];
    const float* bnv  = (const float*)d_in[13];
    const float* Wout = (const float*)d_in[14];
    const float* bout = (const float*)d_in[15];
    const float* Wci  = (const float*)d_in[16];
    const float* bci  = (const float*)d_in[17];
    const float* Wb3a = (const float*)d_in[18];
    const float* bb3a = (const float*)d_in[19];
    const float* Wb3b = (const float*)d_in[20];
    const float* bb3b = (const float*)d_in[21];
    const float* Wcls = (const float*)d_in[22];
    const float* bcls = (const float*)d_in[23];

    char* ws = (char*)d_ws;
    int* deg_out = (int*)(ws + OFF_DEG_OUT);
    int* deg_in  = (int*)(ws + OFF_DEG_IN);
    float* n_out = (float*)(ws + OFF_NOUT);
    float* n_inp = (float*)(ws + OFF_NIN);
    int* row_ptr = (int*)(ws + OFF_ROWPTR);
    int* cursor  = (int*)(ws + OFF_CURSOR);
    int* csr_src = (int*)(ws + OFF_CSRS);
    int* bsum    = (int*)(ws + OFF_BSUM);
    unsigned short* wt1   = (unsigned short*)(ws + OFF_WT1);
    unsigned short* wt2   = (unsigned short*)(ws + OFF_WT2);
    unsigned short* wta   = (unsigned short*)(ws + OFF_WTA);
    unsigned short* wtb   = (unsigned short*)(ws + OFF_WTB);
    unsigned short* wtcls = (unsigned short*)(ws + OFF_WTCLS);
    float* bns = (float*)(ws + OFF_BNS);
    float* bnh = (float*)(ws + OFF_BNH);
    float* T   = (float*)(ws + OFF_T);
    float* R3  = (float*)(ws + OFF_R3);
    unsigned short* h1s = (unsigned short*)(ws + OFF_H1S);

    float* h3d_out   = (float*)d_out;
    float* label_out = (float*)d_out + (size_t)NN * 3;

    hipMemsetAsync(ws, 0, ZERO_BYTES, stream);   // deg_out, deg_in

    k_deg<<<EBLK, 256, 0, stream>>>(src, dst, deg_out, deg_in);
    k_scan1<<<NBLK, 256, 0, stream>>>(deg_in, row_ptr, bsum);
    k_scan2<<<1, 1024, 0, stream>>>(bsum);
    k_scan3<<<NBLK, 256, 0, stream>>>(row_ptr, bsum, cursor, deg_out, deg_in, n_out, n_inp);
    k_fill<<<EBLK, 256, 0, stream>>>(src, dst, cursor, csr_src);
    k_prep<<<dim3(256, 6), 256, 0, stream>>>(Wc1, Wc2, Wb3a, Wb3b, wt1, wt2, wta, wtb,
                                             Wcls, wtcls, bng, bnb, bnm, bnv, bns, bnh);
    k_rowstats<<<NBLK, 256, 0, stream>>>(row_ptr, csr_src, n_out, n_inp, nf, T);

    k_conv1<<<NN / 64, 256, 0, stream>>>(T, nf, Wemb, bemb, wt1, bc1, bns, bnh,
                                         Wout, n_out, h1s, R3);
    k_conv2<<<NN / 64, 256, 0, stream>>>(row_ptr, csr_src, n_inp, h1s, wt2, bc2,
                                         bns + 512, bnh + 512, Wout, bout, R3, h3d_out);
    k_head<<<GG / 64, 256, 0, stream>>>(n2g, h3d_out, Wci, bci, wta, bb3a, wtb, bb3b,
                                        wtcls, bcls, bns, bnh, label_out);
}